// Round 15
// baseline (247.827 us; speedup 1.0000x reference)
//
#include <hip/hip_runtime.h>
#include <hip/hip_bf16.h>
#include <hip/hip_fp16.h>
#include <type_traits>

// combined bucket space: um buckets width 256 -> 79; mu buckets width 1024 -> 98
#define NB_UM 79
#define NB_MU 98
#define NBALL 177
#define NBLK 256
#define CAST_BLKS 64

using f16x8 = __attribute__((ext_vector_type(8))) _Float16;
using f32x4 = __attribute__((ext_vector_type(4))) float;

// ---------------- pass 1: per-(bucket,block) histogram + fp16 casts (merged) ----------------

__global__ __launch_bounds__(1024) void hist_cast(const int* __restrict__ dst_um,
                                                  const int* __restrict__ dst_mu,
                                                  int* __restrict__ histM, int E, int chunk,
                                                  const float* __restrict__ xu,
                                                  __half* __restrict__ xhu, int nu,
                                                  const float* __restrict__ xm,
                                                  __half* __restrict__ xhm, int nm) {
    if ((int)blockIdx.x >= NBLK) {
        // cast blocks
        int i = ((int)blockIdx.x - NBLK) * 1024 + threadIdx.x;
        int st = CAST_BLKS * 1024;
        for (int k = i; k < nu / 2; k += st) {
            float2 v = ((const float2*)xu)[k];
            ((__half2*)xhu)[k] = __floats2half2_rn(v.x, v.y);
        }
        for (int k = i; k < nm / 2; k += st) {
            float2 v = ((const float2*)xm)[k];
            ((__half2*)xhm)[k] = __floats2half2_rn(v.x, v.y);
        }
        return;
    }
    __shared__ int h[NBALL];
    for (int i = threadIdx.x; i < NBALL; i += 1024) h[i] = 0;
    __syncthreads();
    int blk = blockIdx.x;
    int s = blk * chunk, e = min(E, s + chunk);
    if (s < e) {
        int n4 = (e - s) >> 2;
        const int4* du4 = (const int4*)(dst_um + s);
        const int4* dm4 = (const int4*)(dst_mu + s);
        for (int i = threadIdx.x; i < n4; i += 1024) {
            int4 d = du4[i];
            atomicAdd(&h[d.x >> 8], 1);
            atomicAdd(&h[d.y >> 8], 1);
            atomicAdd(&h[d.z >> 8], 1);
            atomicAdd(&h[d.w >> 8], 1);
            int4 m = dm4[i];
            atomicAdd(&h[NB_UM + (m.x >> 10)], 1);
            atomicAdd(&h[NB_UM + (m.y >> 10)], 1);
            atomicAdd(&h[NB_UM + (m.z >> 10)], 1);
            atomicAdd(&h[NB_UM + (m.w >> 10)], 1);
        }
        for (int i = s + (n4 << 2) + threadIdx.x; i < e; i += 1024) {
            atomicAdd(&h[dst_um[i] >> 8], 1);
            atomicAdd(&h[NB_UM + (dst_mu[i] >> 10)], 1);
        }
    }
    __syncthreads();
    for (int i = threadIdx.x; i < NBALL; i += 1024) histM[i * NBLK + blk] = h[i];
}

// ---------------- pass 2: per-bucket scan over blocks + bucket-total scan (merged) ----------------

__global__ __launch_bounds__(1024) void totals_scan(int* __restrict__ histM,
                                                    int* __restrict__ boff,
                                                    int* __restrict__ off_um, int NM,
                                                    int* __restrict__ off_mu, int NU, int E) {
    __shared__ int sbt[NBALL];
    __shared__ int sdata[256];
    int t = threadIdx.x;
    int wid = t >> 6, lane = t & 63;
    // phase A: per-bucket exclusive scan of 256 block-counts (one wave per bucket)
    for (int w = wid; w < NBALL; w += 16) {
        int* row = histM + w * NBLK;
        int v[4];
        int s = 0;
#pragma unroll
        for (int i = 0; i < 4; i++) {
            int c = row[lane * 4 + i];
            v[i] = s;
            s += c;
        }
        int incl = s;
        for (int d = 1; d < 64; d <<= 1) {
            int y = __shfl_up(incl, d, 64);
            if (lane >= d) incl += y;
        }
        int excl = incl - s;
#pragma unroll
        for (int i = 0; i < 4; i++) row[lane * 4 + i] = excl + v[i];
        if (lane == 63) sbt[w] = incl;
    }
    __syncthreads();
    // phase B: exclusive scan of the NBALL totals (threads 0..255 hold data)
    int v0 = 0;
    if (t < 256) {
        v0 = (t < NBALL) ? sbt[t] : 0;
        sdata[t] = v0;
    }
    __syncthreads();
    for (int d = 1; d < 256; d <<= 1) {
        int y = 0;
        if (t < 256 && t >= d) y = sdata[t - d];
        __syncthreads();
        if (t < 256) sdata[t] += y;
        __syncthreads();
    }
    if (t < NBALL) boff[t] = sdata[t] - v0;
    if (t == 0) {
        boff[NBALL] = 2 * E;
        off_um[NM] = E;
        off_mu[NU] = E;
    }
}

// ---------------- pass 3: partition (block-private cursors; cur = histM + boff) ----------------

__global__ __launch_bounds__(1024) void partition2(const int* __restrict__ src_um,
                                                   const int* __restrict__ dst_um,
                                                   const int* __restrict__ src_mu,
                                                   const int* __restrict__ dst_mu,
                                                   const int* __restrict__ histM,
                                                   const int* __restrict__ boff,
                                                   int* __restrict__ tmp, int E, int chunk) {
    __shared__ int cur[NBALL];
    int blk = blockIdx.x;
    for (int i = threadIdx.x; i < NBALL; i += 1024)
        cur[i] = histM[i * NBLK + blk] + boff[i];
    __syncthreads();
    int s = blk * chunk, e = min(E, s + chunk);
    if (s >= e) return;
    int n4 = (e - s) >> 2;
    const int4* su4 = (const int4*)(src_um + s);
    const int4* du4 = (const int4*)(dst_um + s);
    const int4* sm4 = (const int4*)(src_mu + s);
    const int4* dm4 = (const int4*)(dst_mu + s);
    for (int i = threadIdx.x; i < n4; i += 1024) {
        int4 sv = su4[i];
        int4 dv = du4[i];
        int p;
        p = atomicAdd(&cur[dv.x >> 8], 1); tmp[p] = sv.x | ((dv.x & 255) << 20);
        p = atomicAdd(&cur[dv.y >> 8], 1); tmp[p] = sv.y | ((dv.y & 255) << 20);
        p = atomicAdd(&cur[dv.z >> 8], 1); tmp[p] = sv.z | ((dv.z & 255) << 20);
        p = atomicAdd(&cur[dv.w >> 8], 1); tmp[p] = sv.w | ((dv.w & 255) << 20);
        int4 sv2 = sm4[i];
        int4 dv2 = dm4[i];
        p = atomicAdd(&cur[NB_UM + (dv2.x >> 10)], 1); tmp[p] = sv2.x | ((dv2.x & 1023) << 20);
        p = atomicAdd(&cur[NB_UM + (dv2.y >> 10)], 1); tmp[p] = sv2.y | ((dv2.y & 1023) << 20);
        p = atomicAdd(&cur[NB_UM + (dv2.z >> 10)], 1); tmp[p] = sv2.z | ((dv2.z & 1023) << 20);
        p = atomicAdd(&cur[NB_UM + (dv2.w >> 10)], 1); tmp[p] = sv2.w | ((dv2.w & 1023) << 20);
    }
    for (int i = s + (n4 << 2) + threadIdx.x; i < e; i += 1024) {
        int d = dst_um[i];
        int p = atomicAdd(&cur[d >> 8], 1);
        tmp[p] = src_um[i] | ((d & 255) << 20);
        int d2 = dst_mu[i];
        int q = atomicAdd(&cur[NB_UM + (d2 >> 10)], 1);
        tmp[q] = src_mu[i] | ((d2 & 1023) << 20);
    }
}

// ---------------- pass 4: per-bucket CSR scatter, both sides in one grid ----------------

__global__ __launch_bounds__(1024) void scatter_both(const int* __restrict__ tmp,
                                                     const int* __restrict__ boff,
                                                     int* __restrict__ off_um,
                                                     int* __restrict__ csr_um, int NM,
                                                     int* __restrict__ off_mu,
                                                     int* __restrict__ csr_mu, int NU, int E) {
    __shared__ int lcnt[1024];
    __shared__ int lcur[1024];
    __shared__ int sdata[1024];
    int b = blockIdx.x;
    int um = (b < NB_UM);
    int W = um ? 256 : 1024;
    int n = um ? NM : NU;
    int sub = um ? 0 : E;
    int* off = um ? off_um : off_mu;
    int* csr = um ? csr_um : csr_mu;
    int rowbase = (um ? b : (b - NB_UM)) * W;
    int t = threadIdx.x;
    int s = boff[b], e = boff[b + 1];
    for (int j = t; j < W; j += 1024) lcnt[j] = 0;
    __syncthreads();
    for (int i = s + t; i < e; i += 1024) atomicAdd(&lcnt[tmp[i] >> 20], 1);
    __syncthreads();
    int myc = (t < W) ? lcnt[t] : 0;
    sdata[t] = myc;
    __syncthreads();
    for (int d = 1; d < 1024; d <<= 1) {
        int y = (t >= d) ? sdata[t - d] : 0;
        __syncthreads();
        sdata[t] += y;
        __syncthreads();
    }
    if (t < W) lcur[t] = s + sdata[t] - myc;
    __syncthreads();
    for (int j = t; j < W; j += 1024)
        if (rowbase + j < n) off[rowbase + j] = lcur[j] - sub;
    __syncthreads();
    for (int i = s + t; i < e; i += 1024) {
        int vv = tmp[i];
        int p = atomicAdd(&lcur[vv >> 20], 1);
        csr[p - sub] = vv & 0xFFFFF;
    }
}

// ---------------- segment mean body (fp16 gather -> fp16 mean out) ----------------

__device__ __forceinline__ void acc8(float* a, uint4 r) {
    const __half2* h = reinterpret_cast<const __half2*>(&r);
#pragma unroll
    for (int j = 0; j < 4; j++) {
        float2 f = __half22float2(h[j]);
        a[2 * j] += f.x;
        a[2 * j + 1] += f.y;
    }
}

template <int D>
__device__ __forceinline__ void agg_body(const int* __restrict__ csr,
                                         const int* __restrict__ off,
                                         const __half* __restrict__ xh,
                                         __half* __restrict__ out, int nrows,
                                         int bid, int nblocks) {
    constexpr int L = D / 8;  // lanes per row
    int gid = (bid * 256 + (int)threadIdx.x) / L;
    int lg = threadIdx.x & (L - 1);
    int ngroups = (nblocks * 256) / L;
    int c8 = lg * 8;
    for (int row = gid; row < nrows; row += ngroups) {
        int s = off[row], e = off[row + 1];
        float a[8] = {0.f, 0.f, 0.f, 0.f, 0.f, 0.f, 0.f, 0.f};
        int k = s;
        for (; k + 4 <= e; k += 4) {
            int i0 = csr[k], i1 = csr[k + 1], i2 = csr[k + 2], i3 = csr[k + 3];
            uint4 r0 = *(const uint4*)&xh[(long)i0 * D + c8];
            uint4 r1 = *(const uint4*)&xh[(long)i1 * D + c8];
            uint4 r2 = *(const uint4*)&xh[(long)i2 * D + c8];
            uint4 r3 = *(const uint4*)&xh[(long)i3 * D + c8];
            acc8(a, r0); acc8(a, r1); acc8(a, r2); acc8(a, r3);
        }
        for (; k < e; ++k) {
            uint4 r0 = *(const uint4*)&xh[(long)csr[k] * D + c8];
            acc8(a, r0);
        }
        float inv = 1.0f / fmaxf((float)(e - s), 1.0f);
        __half2 h0 = __floats2half2_rn(a[0] * inv, a[1] * inv);
        __half2 h1 = __floats2half2_rn(a[2] * inv, a[3] * inv);
        __half2 h2 = __floats2half2_rn(a[4] * inv, a[5] * inv);
        __half2 h3 = __floats2half2_rn(a[6] * inv, a[7] * inv);
        uint4 w;
        w.x = *(unsigned*)&h0; w.y = *(unsigned*)&h1;
        w.z = *(unsigned*)&h2; w.w = *(unsigned*)&h3;
        *(uint4*)&out[(long)row * D + c8] = w;
    }
}

// layer-1 merged aggs: blocks [0,g1): um D=32; [g1,..): mu D=64
__global__ __launch_bounds__(256) void agg_dual_l1(const int* __restrict__ csr_um,
                                                   const int* __restrict__ off_um,
                                                   const __half* __restrict__ xh_u,
                                                   __half* __restrict__ A_m, int NM, int g1,
                                                   const int* __restrict__ csr_mu,
                                                   const int* __restrict__ off_mu,
                                                   const __half* __restrict__ xh_m,
                                                   __half* __restrict__ A_u, int NU) {
    if ((int)blockIdx.x < g1)
        agg_body<32>(csr_um, off_um, xh_u, A_m, NM, blockIdx.x, g1);
    else
        agg_body<64>(csr_mu, off_mu, xh_m, A_u, NU, blockIdx.x - g1, gridDim.x - g1);
}

// layer-2 merged aggs: both D=64
__global__ __launch_bounds__(256) void agg_dual_l2(const int* __restrict__ csr_um,
                                                   const int* __restrict__ off_um,
                                                   const __half* __restrict__ Hh_u,
                                                   __half* __restrict__ A_m, int NM, int g1,
                                                   const int* __restrict__ csr_mu,
                                                   const int* __restrict__ off_mu,
                                                   const __half* __restrict__ Hh_m,
                                                   __half* __restrict__ A_u, int NU) {
    if ((int)blockIdx.x < g1)
        agg_body<64>(csr_um, off_um, Hh_u, A_m, NM, blockIdx.x, g1);
    else
        agg_body<64>(csr_mu, off_mu, Hh_m, A_u, NU, blockIdx.x - g1, gridDim.x - g1);
}

// ---------------- dense via MFMA body (mean is fp16; xd fp32 or fp16) ----------------

template <int Dm, int Dd, bool RELU, typename TX>
__device__ __forceinline__ void dense_body(char* smemraw,
                                           const __half* __restrict__ mean,
                                           const TX* __restrict__ xd,
                                           const float* __restrict__ Wl,
                                           const float* __restrict__ Wr,
                                           const float* __restrict__ bias,
                                           __half* __restrict__ out, int n, int bid) {
    constexpr int K = Dm + Dd;     // 96 or 128
    constexpr int SAP = K + 8;
    _Float16* sA = (_Float16*)smemraw;
    _Float16* sWt = sA + 64 * SAP;
    float* sb = (float*)(sWt + 64 * SAP);
    int t = threadIdx.x;
    int R0 = bid * 64;

    for (int i = t; i < K * 16; i += 256) {
        int k = i >> 4, c = (i & 15) * 4;
        float4 v = (k < Dm) ? *(const float4*)&Wl[k * 64 + c]
                            : *(const float4*)&Wr[(k - Dm) * 64 + c];
        sWt[(c + 0) * SAP + k] = (_Float16)v.x;
        sWt[(c + 1) * SAP + k] = (_Float16)v.y;
        sWt[(c + 2) * SAP + k] = (_Float16)v.z;
        sWt[(c + 3) * SAP + k] = (_Float16)v.w;
    }
    if (t < 64) sb[t] = bias[t];
    constexpr int QR = K / 4;
    for (int i = t; i < 64 * QR; i += 256) {
        int r = i / QR, c = (i % QR) * 4;
        int gr = R0 + r;
        _Float16* p = &sA[r * SAP + c];
        if (gr < n) {
            if (c < Dm) {
                *(uint2*)p = *(const uint2*)&mean[(long)gr * Dm + c];
            } else {
                if constexpr (std::is_same<TX, __half>::value) {
                    *(uint2*)p = *(const uint2*)&xd[(long)gr * Dd + (c - Dm)];
                } else {
                    float4 v = *(const float4*)&xd[(long)gr * Dd + (c - Dm)];
                    p[0] = (_Float16)v.x; p[1] = (_Float16)v.y;
                    p[2] = (_Float16)v.z; p[3] = (_Float16)v.w;
                }
            }
        } else {
            p[0] = (_Float16)0.f; p[1] = (_Float16)0.f;
            p[2] = (_Float16)0.f; p[3] = (_Float16)0.f;
        }
    }
    __syncthreads();

    int w = t >> 6, lane = t & 63;
    int lr = lane & 15, lg = lane >> 4;
    f32x4 acc[4];
#pragma unroll
    for (int nt = 0; nt < 4; nt++) {
        float bb = sb[16 * nt + lr];
        acc[nt][0] = bb; acc[nt][1] = bb; acc[nt][2] = bb; acc[nt][3] = bb;
    }
    int arow = 16 * w + lr;
#pragma unroll
    for (int kk = 0; kk < K / 32; kk++) {
        int k0 = kk * 32 + 8 * lg;
        f16x8 a = *(const f16x8*)&sA[arow * SAP + k0];
#pragma unroll
        for (int nt = 0; nt < 4; nt++) {
            f16x8 b = *(const f16x8*)&sWt[(16 * nt + lr) * SAP + k0];
            acc[nt] = __builtin_amdgcn_mfma_f32_16x16x32_f16(a, b, acc[nt], 0, 0, 0);
        }
    }
#pragma unroll
    for (int nt = 0; nt < 4; nt++) {
#pragma unroll
        for (int r = 0; r < 4; r++) {
            int gr = R0 + 16 * w + lg * 4 + r;
            if (gr >= n) continue;
            float vv = acc[nt][r];
            if (RELU) vv = fmaxf(vv, 0.f);
            out[(long)gr * 64 + 16 * nt + lr] = __float2half(vv);
        }
    }
}

#define DENSE_SMEM_BYTES (64 * 136 * 2 * 2 + 256)

// layer-1 merged denses: [0,g1): um (K=96), rest: mu (K=128)
__global__ __launch_bounds__(256) void dense_dual_l1(const __half* __restrict__ A_m,
                                                     const float* __restrict__ x_movie,
                                                     const float* __restrict__ W1l_um,
                                                     const float* __restrict__ W1r_um,
                                                     const float* __restrict__ b1_um,
                                                     __half* __restrict__ Hh_m, int NM, int g1,
                                                     const __half* __restrict__ A_u,
                                                     const float* __restrict__ x_user,
                                                     const float* __restrict__ W1l_mu,
                                                     const float* __restrict__ W1r_mu,
                                                     const float* __restrict__ b1_mu,
                                                     __half* __restrict__ Hh_u, int NU) {
    __shared__ __align__(16) char smem[DENSE_SMEM_BYTES];
    if ((int)blockIdx.x < g1)
        dense_body<32, 64, true, float>(smem, A_m, x_movie, W1l_um, W1r_um, b1_um,
                                        Hh_m, NM, blockIdx.x);
    else
        dense_body<64, 32, true, float>(smem, A_u, x_user, W1l_mu, W1r_mu, b1_mu,
                                        Hh_u, NU, blockIdx.x - g1);
}

// layer-2 merged denses: both K=128, fp16 in-place output over the mean buffers
__global__ __launch_bounds__(256) void dense_dual_l2(__half* __restrict__ A_m,
                                                     const __half* __restrict__ Hh_m,
                                                     const float* __restrict__ W2l_um,
                                                     const float* __restrict__ W2r_um,
                                                     const float* __restrict__ b2_um,
                                                     int NM, int g1,
                                                     __half* __restrict__ A_u,
                                                     const __half* __restrict__ Hh_u,
                                                     const float* __restrict__ W2l_mu,
                                                     const float* __restrict__ W2r_mu,
                                                     const float* __restrict__ b2_mu,
                                                     int NU) {
    __shared__ __align__(16) char smem[DENSE_SMEM_BYTES];
    if ((int)blockIdx.x < g1)
        dense_body<64, 64, false, __half>(smem, A_m, Hh_m, W2l_um, W2r_um, b2_um,
                                          A_m, NM, blockIdx.x);
    else
        dense_body<64, 64, false, __half>(smem, A_u, Hh_u, W2l_mu, W2r_mu, b2_mu,
                                          A_u, NU, blockIdx.x - g1);
}

// ---------------- merged head projections (z is fp16) ----------------

__global__ __launch_bounds__(256) void proj_dual(const __half* __restrict__ zu,
                                                 const __half* __restrict__ zm,
                                                 const float* __restrict__ Wlin,
                                                 const float* __restrict__ blin,
                                                 float2* __restrict__ pu,
                                                 float2* __restrict__ pm,
                                                 int NU, int NM, int gu) {
    int isu = ((int)blockIdx.x < gu);
    const __half* z = isu ? zu : zm;
    float2* p = isu ? pu : pm;
    int n = isu ? NU : NM;
    int woff = isu ? 0 : 64;
    int bid = isu ? blockIdx.x : blockIdx.x - gu;
    __shared__ float sW0[64], sW1[64];
    int t = threadIdx.x;
    if (t < 64) {
        sW0[t] = Wlin[(woff + t) * 2 + 0];
        sW1[t] = Wlin[(woff + t) * 2 + 1];
    }
    __syncthreads();
    float b0 = isu ? blin[0] : 0.f;
    float b1 = isu ? blin[1] : 0.f;
    int lane = t & 63;
    int w = t >> 6;
    int lr = lane & 15, q = lane >> 4;
    int row = bid * 16 + w * 4 + q;
    if (row >= n) return;
    uint2 raw = *(const uint2*)&z[(long)row * 64 + lr * 4];
    __half2 z01 = *(__half2*)&raw.x;
    __half2 z23 = *(__half2*)&raw.y;
    float2 f01 = __half22float2(z01);
    float2 f23 = __half22float2(z23);
    float p0 = f01.x * sW0[lr * 4] + f01.y * sW0[lr * 4 + 1] + f23.x * sW0[lr * 4 + 2] + f23.y * sW0[lr * 4 + 3];
    float p1 = f01.x * sW1[lr * 4] + f01.y * sW1[lr * 4 + 1] + f23.x * sW1[lr * 4 + 2] + f23.y * sW1[lr * 4 + 3];
#pragma unroll
    for (int m = 1; m < 16; m <<= 1) {
        p0 += __shfl_xor(p0, m, 64);
        p1 += __shfl_xor(p1, m, 64);
    }
    if (lr == 0) p[row] = make_float2(p0 + b0, p1 + b1);
}

// ---------------- head: two 8B gathers + softplus per label ----------------

__global__ __launch_bounds__(256) void head_gather(const float2* __restrict__ pu,
                                                   const float2* __restrict__ pm,
                                                   const int* __restrict__ lrow,
                                                   const int* __restrict__ lcol,
                                                   float* __restrict__ out, int B) {
    int i = blockIdx.x * blockDim.x + threadIdx.x;
    int st = gridDim.x * blockDim.x;
    for (int b = i; b < B; b += st) {
        float2 a = pu[lrow[b]];
        float2 d = pm[lcol[b]];
        float m = a.x + d.x;
        float x = a.y + d.y;
        float sp = fmaxf(x, 0.f) + log1pf(expf(-fabsf(x)));
        out[b] = m;
        out[B + b] = sp + 1e-6f;
    }
}

// ---------------- launch ----------------

extern "C" void kernel_launch(void* const* d_in, const int* in_sizes, int n_in,
                              void* d_out, int out_size, void* d_ws, size_t ws_size,
                              hipStream_t stream) {
    const float* x_user  = (const float*)d_in[0];
    const float* x_movie = (const float*)d_in[1];
    const int* src_um = (const int*)d_in[2];
    const int* dst_um = (const int*)d_in[3];
    const int* src_mu = (const int*)d_in[4];
    const int* dst_mu = (const int*)d_in[5];
    const int* lrow = (const int*)d_in[6];
    const int* lcol = (const int*)d_in[7];
    const float* W1_um_l = (const float*)d_in[8];
    const float* b1_um   = (const float*)d_in[9];
    const float* W1_um_r = (const float*)d_in[10];
    const float* W1_mu_l = (const float*)d_in[11];
    const float* b1_mu   = (const float*)d_in[12];
    const float* W1_mu_r = (const float*)d_in[13];
    const float* W2_um_l = (const float*)d_in[14];
    const float* b2_um   = (const float*)d_in[15];
    const float* W2_um_r = (const float*)d_in[16];
    const float* W2_mu_l = (const float*)d_in[17];
    const float* b2_mu   = (const float*)d_in[18];
    const float* W2_mu_r = (const float*)d_in[19];
    const float* W_lin   = (const float*)d_in[20];
    const float* b_lin   = (const float*)d_in[21];
    float* out = (float*)d_out;

    const int E  = in_sizes[2];
    const int B  = in_sizes[6];
    const int NU = in_sizes[0] / 32;   // 100000
    const int NM = in_sizes[1] / 64;   // 20000

    char* wsp = (char*)d_ws;
    size_t o = 0;
    auto alloc = [&](size_t bytes) {
        size_t p = o;
        o += (bytes + 255) & ~(size_t)255;
        return (void*)(wsp + p);
    };
    int* off_um = (int*)alloc((size_t)(NM + 1) * 4);
    int* off_mu = (int*)alloc((size_t)(NU + 1) * 4);
    int* boff   = (int*)alloc((NBALL + 1) * 4);
    int* csr_um = (int*)alloc((size_t)E * 4);
    int* csr_mu = (int*)alloc((size_t)E * 4);
    int* tmp    = (int*)alloc((size_t)2 * E * 4);        // packed bucketed edges
    __half* A_m  = (__half*)alloc((size_t)NM * 64 * 2);  // movie mean / z_movie (fp16)
    __half* A_u  = (__half*)alloc((size_t)NU * 64 * 2);  // user mean / z_user (fp16)
    __half* Hh_m = (__half*)alloc((size_t)NM * 64 * 2);  // h_movie fp16
    __half* Hh_u = (__half*)alloc((size_t)NU * 64 * 2);  // h_user fp16
    __half* xh_u = (__half*)alloc((size_t)NU * 32 * 2);  // x_user fp16
    __half* xh_m = (__half*)alloc((size_t)NM * 64 * 2);  // x_movie fp16
    float2* pu  = (float2*)alloc((size_t)NU * 8);        // user head projection
    float2* pm  = (float2*)alloc((size_t)NM * 8);        // movie head projection
    (void)ws_size;

    // histM aliases A_m: 177*256*4 = 181 KB <= 2.56 MB; dead after partition2,
    // A_m first written by agg_dual_l1 (later).
    int* histM = (int*)A_m;

    const int chunk = (((E + NBLK - 1) / NBLK) + 3) & ~3;  // multiple of 4

    // 1) CSR build (block-private radix partition) + fp16 casts merged into pass 1
    hist_cast<<<NBLK + CAST_BLKS, 1024, 0, stream>>>(dst_um, dst_mu, histM, E, chunk,
                                                     x_user, xh_u, NU * 32,
                                                     x_movie, xh_m, NM * 64);
    totals_scan<<<1, 1024, 0, stream>>>(histM, boff, off_um, NM, off_mu, NU, E);
    partition2<<<NBLK, 1024, 0, stream>>>(src_um, dst_um, src_mu, dst_mu, histM, boff,
                                          tmp, E, chunk);
    scatter_both<<<NBALL, 1024, 0, stream>>>(tmp, boff, off_um, csr_um, NM,
                                             off_mu, csr_mu, NU, E);

    // 2) layer 1: merged aggs, then merged denses
    {
        int g1 = (NM * 4 + 255) / 256;   // um D=32 groups
        int g2 = (NU * 8 + 255) / 256;   // mu D=64 groups
        agg_dual_l1<<<g1 + g2, 256, 0, stream>>>(csr_um, off_um, xh_u, A_m, NM, g1,
                                                 csr_mu, off_mu, xh_m, A_u, NU);
        int d1 = (NM + 63) / 64, d2 = (NU + 63) / 64;
        dense_dual_l1<<<d1 + d2, 256, 0, stream>>>(A_m, x_movie, W1_um_l, W1_um_r, b1_um,
                                                   Hh_m, NM, d1,
                                                   A_u, x_user, W1_mu_l, W1_mu_r, b1_mu,
                                                   Hh_u, NU);
    }

    // 3) layer 2: merged aggs, then merged denses (fp16 in-place over mean buffers)
    {
        int g1 = (NM * 8 + 255) / 256;
        int g2 = (NU * 8 + 255) / 256;
        agg_dual_l2<<<g1 + g2, 256, 0, stream>>>(csr_um, off_um, Hh_u, A_m, NM, g1,
                                                 csr_mu, off_mu, Hh_m, A_u, NU);
        int d1 = (NM + 63) / 64, d2 = (NU + 63) / 64;
        dense_dual_l2<<<d1 + d2, 256, 0, stream>>>(A_m, Hh_m, W2_um_l, W2_um_r, b2_um, NM, d1,
                                                   A_u, Hh_u, W2_mu_l, W2_mu_r, b2_mu, NU);
    }

    // 4) head: merged projections, then gather
    {
        int gu = (NU + 15) / 16, gm = (NM + 15) / 16;
        proj_dual<<<gu + gm, 256, 0, stream>>>(A_u, A_m, W_lin, b_lin, pu, pm, NU, NM, gu);
    }
    head_gather<<<1024, 256, 0, stream>>>(pu, pm, lrow, lcol, out, B);
}

// Round 16
// 238.994 us; speedup vs baseline: 1.0370x; 1.0370x over previous
//
#include <hip/hip_runtime.h>
#include <hip/hip_bf16.h>
#include <hip/hip_fp16.h>
#include <type_traits>

// combined bucket space: um buckets width 256 -> 79; mu buckets width 1024 -> 98
#define NB_UM 79
#define NB_MU 98
#define NBALL 177
#define NBLK 256
#define CAST_BLKS 64

using f16x8 = __attribute__((ext_vector_type(8))) _Float16;
using f32x4 = __attribute__((ext_vector_type(4))) float;

// ---------------- pass 1: per-(bucket,block) histogram + fp16 casts (merged) ----------------

__global__ __launch_bounds__(1024) void hist_cast(const int* __restrict__ dst_um,
                                                  const int* __restrict__ dst_mu,
                                                  int* __restrict__ histM, int E, int chunk,
                                                  const float* __restrict__ xu,
                                                  __half* __restrict__ xhu, int nu,
                                                  const float* __restrict__ xm,
                                                  __half* __restrict__ xhm, int nm) {
    if ((int)blockIdx.x >= NBLK) {
        int i = ((int)blockIdx.x - NBLK) * 1024 + threadIdx.x;
        int st = CAST_BLKS * 1024;
        for (int k = i; k < nu / 2; k += st) {
            float2 v = ((const float2*)xu)[k];
            ((__half2*)xhu)[k] = __floats2half2_rn(v.x, v.y);
        }
        for (int k = i; k < nm / 2; k += st) {
            float2 v = ((const float2*)xm)[k];
            ((__half2*)xhm)[k] = __floats2half2_rn(v.x, v.y);
        }
        return;
    }
    __shared__ int h[NBALL];
    for (int i = threadIdx.x; i < NBALL; i += 1024) h[i] = 0;
    __syncthreads();
    int blk = blockIdx.x;
    int s = blk * chunk, e = min(E, s + chunk);
    if (s < e) {
        int n4 = (e - s) >> 2;
        const int4* du4 = (const int4*)(dst_um + s);
        const int4* dm4 = (const int4*)(dst_mu + s);
        for (int i = threadIdx.x; i < n4; i += 1024) {
            int4 d = du4[i];
            atomicAdd(&h[d.x >> 8], 1);
            atomicAdd(&h[d.y >> 8], 1);
            atomicAdd(&h[d.z >> 8], 1);
            atomicAdd(&h[d.w >> 8], 1);
            int4 m = dm4[i];
            atomicAdd(&h[NB_UM + (m.x >> 10)], 1);
            atomicAdd(&h[NB_UM + (m.y >> 10)], 1);
            atomicAdd(&h[NB_UM + (m.z >> 10)], 1);
            atomicAdd(&h[NB_UM + (m.w >> 10)], 1);
        }
        for (int i = s + (n4 << 2) + threadIdx.x; i < e; i += 1024) {
            atomicAdd(&h[dst_um[i] >> 8], 1);
            atomicAdd(&h[NB_UM + (dst_mu[i] >> 10)], 1);
        }
    }
    __syncthreads();
    for (int i = threadIdx.x; i < NBALL; i += 1024) histM[i * NBLK + blk] = h[i];
}

// ---------------- pass 2: per-bucket scan over blocks + bucket-total scan (merged) ----------------

__global__ __launch_bounds__(1024) void totals_scan(int* __restrict__ histM,
                                                    int* __restrict__ boff,
                                                    int* __restrict__ off_um, int NM,
                                                    int* __restrict__ off_mu, int NU, int E) {
    __shared__ int sbt[NBALL];
    __shared__ int sdata[256];
    int t = threadIdx.x;
    int wid = t >> 6, lane = t & 63;
    for (int w = wid; w < NBALL; w += 16) {
        int* row = histM + w * NBLK;
        int v[4];
        int s = 0;
#pragma unroll
        for (int i = 0; i < 4; i++) {
            int c = row[lane * 4 + i];
            v[i] = s;
            s += c;
        }
        int incl = s;
        for (int d = 1; d < 64; d <<= 1) {
            int y = __shfl_up(incl, d, 64);
            if (lane >= d) incl += y;
        }
        int excl = incl - s;
#pragma unroll
        for (int i = 0; i < 4; i++) row[lane * 4 + i] = excl + v[i];
        if (lane == 63) sbt[w] = incl;
    }
    __syncthreads();
    int v0 = 0;
    if (t < 256) {
        v0 = (t < NBALL) ? sbt[t] : 0;
        sdata[t] = v0;
    }
    __syncthreads();
    for (int d = 1; d < 256; d <<= 1) {
        int y = 0;
        if (t < 256 && t >= d) y = sdata[t - d];
        __syncthreads();
        if (t < 256) sdata[t] += y;
        __syncthreads();
    }
    if (t < NBALL) boff[t] = sdata[t] - v0;
    if (t == 0) {
        boff[NBALL] = 2 * E;
        off_um[NM] = E;
        off_mu[NU] = E;
    }
}

// ---------------- pass 3: partition (block-private cursors; cur = histM + boff) ----------------

__global__ __launch_bounds__(1024) void partition2(const int* __restrict__ src_um,
                                                   const int* __restrict__ dst_um,
                                                   const int* __restrict__ src_mu,
                                                   const int* __restrict__ dst_mu,
                                                   const int* __restrict__ histM,
                                                   const int* __restrict__ boff,
                                                   int* __restrict__ tmp, int E, int chunk) {
    __shared__ int cur[NBALL];
    int blk = blockIdx.x;
    for (int i = threadIdx.x; i < NBALL; i += 1024)
        cur[i] = histM[i * NBLK + blk] + boff[i];
    __syncthreads();
    int s = blk * chunk, e = min(E, s + chunk);
    if (s >= e) return;
    int n4 = (e - s) >> 2;
    const int4* su4 = (const int4*)(src_um + s);
    const int4* du4 = (const int4*)(dst_um + s);
    const int4* sm4 = (const int4*)(src_mu + s);
    const int4* dm4 = (const int4*)(dst_mu + s);
    for (int i = threadIdx.x; i < n4; i += 1024) {
        int4 sv = su4[i];
        int4 dv = du4[i];
        int p;
        p = atomicAdd(&cur[dv.x >> 8], 1); tmp[p] = sv.x | ((dv.x & 255) << 20);
        p = atomicAdd(&cur[dv.y >> 8], 1); tmp[p] = sv.y | ((dv.y & 255) << 20);
        p = atomicAdd(&cur[dv.z >> 8], 1); tmp[p] = sv.z | ((dv.z & 255) << 20);
        p = atomicAdd(&cur[dv.w >> 8], 1); tmp[p] = sv.w | ((dv.w & 255) << 20);
        int4 sv2 = sm4[i];
        int4 dv2 = dm4[i];
        p = atomicAdd(&cur[NB_UM + (dv2.x >> 10)], 1); tmp[p] = sv2.x | ((dv2.x & 1023) << 20);
        p = atomicAdd(&cur[NB_UM + (dv2.y >> 10)], 1); tmp[p] = sv2.y | ((dv2.y & 1023) << 20);
        p = atomicAdd(&cur[NB_UM + (dv2.z >> 10)], 1); tmp[p] = sv2.z | ((dv2.z & 1023) << 20);
        p = atomicAdd(&cur[NB_UM + (dv2.w >> 10)], 1); tmp[p] = sv2.w | ((dv2.w & 1023) << 20);
    }
    for (int i = s + (n4 << 2) + threadIdx.x; i < e; i += 1024) {
        int d = dst_um[i];
        int p = atomicAdd(&cur[d >> 8], 1);
        tmp[p] = src_um[i] | ((d & 255) << 20);
        int d2 = dst_mu[i];
        int q = atomicAdd(&cur[NB_UM + (d2 >> 10)], 1);
        tmp[q] = src_mu[i] | ((d2 & 1023) << 20);
    }
}

// ---------------- pass 4: per-bucket CSR scatter, both sides in one grid ----------------

__global__ __launch_bounds__(1024) void scatter_both(const int* __restrict__ tmp,
                                                     const int* __restrict__ boff,
                                                     int* __restrict__ off_um,
                                                     int* __restrict__ csr_um, int NM,
                                                     int* __restrict__ off_mu,
                                                     int* __restrict__ csr_mu, int NU, int E) {
    __shared__ int lcnt[1024];
    __shared__ int lcur[1024];
    __shared__ int sdata[1024];
    int b = blockIdx.x;
    int um = (b < NB_UM);
    int W = um ? 256 : 1024;
    int n = um ? NM : NU;
    int sub = um ? 0 : E;
    int* off = um ? off_um : off_mu;
    int* csr = um ? csr_um : csr_mu;
    int rowbase = (um ? b : (b - NB_UM)) * W;
    int t = threadIdx.x;
    int s = boff[b], e = boff[b + 1];
    for (int j = t; j < W; j += 1024) lcnt[j] = 0;
    __syncthreads();
    for (int i = s + t; i < e; i += 1024) atomicAdd(&lcnt[tmp[i] >> 20], 1);
    __syncthreads();
    int myc = (t < W) ? lcnt[t] : 0;
    sdata[t] = myc;
    __syncthreads();
    for (int d = 1; d < 1024; d <<= 1) {
        int y = (t >= d) ? sdata[t - d] : 0;
        __syncthreads();
        sdata[t] += y;
        __syncthreads();
    }
    if (t < W) lcur[t] = s + sdata[t] - myc;
    __syncthreads();
    for (int j = t; j < W; j += 1024)
        if (rowbase + j < n) off[rowbase + j] = lcur[j] - sub;
    __syncthreads();
    for (int i = s + t; i < e; i += 1024) {
        int vv = tmp[i];
        int p = atomicAdd(&lcur[vv >> 20], 1);
        csr[p - sub] = vv & 0xFFFFF;
    }
}

// ---------------- segment mean body (fp16 gather -> fp16 mean out, deep ILP) ----------------

__device__ __forceinline__ void acc8(float* a, uint4 r) {
    const __half2* h = reinterpret_cast<const __half2*>(&r);
#pragma unroll
    for (int j = 0; j < 4; j++) {
        float2 f = __half22float2(h[j]);
        a[2 * j] += f.x;
        a[2 * j + 1] += f.y;
    }
}

template <int D>
__device__ __forceinline__ void agg_body(const int* __restrict__ csr,
                                         const int* __restrict__ off,
                                         const __half* __restrict__ xh,
                                         __half* __restrict__ out, int nrows,
                                         int bid, int nblocks) {
    constexpr int L = D / 8;  // lanes per row
    int gid = (bid * 256 + (int)threadIdx.x) / L;
    int lg = threadIdx.x & (L - 1);
    int ngroups = (nblocks * 256) / L;
    int c8 = lg * 8;
    for (int row = gid; row < nrows; row += ngroups) {
        int s = off[row], e = off[row + 1];
        float a[8] = {0.f, 0.f, 0.f, 0.f, 0.f, 0.f, 0.f, 0.f};
        int k = s;
        // 8 independent gathers in flight
        for (; k + 8 <= e; k += 8) {
            uint4 r0 = *(const uint4*)&xh[(long)csr[k + 0] * D + c8];
            uint4 r1 = *(const uint4*)&xh[(long)csr[k + 1] * D + c8];
            uint4 r2 = *(const uint4*)&xh[(long)csr[k + 2] * D + c8];
            uint4 r3 = *(const uint4*)&xh[(long)csr[k + 3] * D + c8];
            uint4 r4 = *(const uint4*)&xh[(long)csr[k + 4] * D + c8];
            uint4 r5 = *(const uint4*)&xh[(long)csr[k + 5] * D + c8];
            uint4 r6 = *(const uint4*)&xh[(long)csr[k + 6] * D + c8];
            uint4 r7 = *(const uint4*)&xh[(long)csr[k + 7] * D + c8];
            acc8(a, r0); acc8(a, r1); acc8(a, r2); acc8(a, r3);
            acc8(a, r4); acc8(a, r5); acc8(a, r6); acc8(a, r7);
        }
        for (; k + 4 <= e; k += 4) {
            uint4 r0 = *(const uint4*)&xh[(long)csr[k + 0] * D + c8];
            uint4 r1 = *(const uint4*)&xh[(long)csr[k + 1] * D + c8];
            uint4 r2 = *(const uint4*)&xh[(long)csr[k + 2] * D + c8];
            uint4 r3 = *(const uint4*)&xh[(long)csr[k + 3] * D + c8];
            acc8(a, r0); acc8(a, r1); acc8(a, r2); acc8(a, r3);
        }
        for (; k < e; ++k) {
            uint4 r0 = *(const uint4*)&xh[(long)csr[k] * D + c8];
            acc8(a, r0);
        }
        float inv = 1.0f / fmaxf((float)(e - s), 1.0f);
        __half2 h0 = __floats2half2_rn(a[0] * inv, a[1] * inv);
        __half2 h1 = __floats2half2_rn(a[2] * inv, a[3] * inv);
        __half2 h2 = __floats2half2_rn(a[4] * inv, a[5] * inv);
        __half2 h3 = __floats2half2_rn(a[6] * inv, a[7] * inv);
        uint4 w;
        w.x = *(unsigned*)&h0; w.y = *(unsigned*)&h1;
        w.z = *(unsigned*)&h2; w.w = *(unsigned*)&h3;
        *(uint4*)&out[(long)row * D + c8] = w;
    }
}

// layer-1 merged aggs: blocks [0,g1): um D=32; [g1,..): mu D=64
__global__ __launch_bounds__(256) void agg_dual_l1(const int* __restrict__ csr_um,
                                                   const int* __restrict__ off_um,
                                                   const __half* __restrict__ xh_u,
                                                   __half* __restrict__ A_m, int NM, int g1,
                                                   const int* __restrict__ csr_mu,
                                                   const int* __restrict__ off_mu,
                                                   const __half* __restrict__ xh_m,
                                                   __half* __restrict__ A_u, int NU) {
    if ((int)blockIdx.x < g1)
        agg_body<32>(csr_um, off_um, xh_u, A_m, NM, blockIdx.x, g1);
    else
        agg_body<64>(csr_mu, off_mu, xh_m, A_u, NU, blockIdx.x - g1, gridDim.x - g1);
}

// layer-2 merged aggs: both D=64
__global__ __launch_bounds__(256) void agg_dual_l2(const int* __restrict__ csr_um,
                                                   const int* __restrict__ off_um,
                                                   const __half* __restrict__ Hh_u,
                                                   __half* __restrict__ A_m, int NM, int g1,
                                                   const int* __restrict__ csr_mu,
                                                   const int* __restrict__ off_mu,
                                                   const __half* __restrict__ Hh_m,
                                                   __half* __restrict__ A_u, int NU) {
    if ((int)blockIdx.x < g1)
        agg_body<64>(csr_um, off_um, Hh_u, A_m, NM, blockIdx.x, g1);
    else
        agg_body<64>(csr_mu, off_mu, Hh_m, A_u, NU, blockIdx.x - g1, gridDim.x - g1);
}

// ---------------- dense via MFMA body (mean fp16; xd fp16) ----------------

template <int Dm, int Dd, bool RELU>
__device__ __forceinline__ void dense_body(char* smemraw,
                                           const __half* __restrict__ mean,
                                           const __half* __restrict__ xd,
                                           const float* __restrict__ Wl,
                                           const float* __restrict__ Wr,
                                           const float* __restrict__ bias,
                                           __half* __restrict__ out, int n, int bid) {
    constexpr int K = Dm + Dd;     // 96 or 128
    constexpr int SAP = K + 8;
    _Float16* sA = (_Float16*)smemraw;
    _Float16* sWt = sA + 64 * SAP;
    float* sb = (float*)(sWt + 64 * SAP);
    int t = threadIdx.x;
    int R0 = bid * 64;

    for (int i = t; i < K * 16; i += 256) {
        int k = i >> 4, c = (i & 15) * 4;
        float4 v = (k < Dm) ? *(const float4*)&Wl[k * 64 + c]
                            : *(const float4*)&Wr[(k - Dm) * 64 + c];
        sWt[(c + 0) * SAP + k] = (_Float16)v.x;
        sWt[(c + 1) * SAP + k] = (_Float16)v.y;
        sWt[(c + 2) * SAP + k] = (_Float16)v.z;
        sWt[(c + 3) * SAP + k] = (_Float16)v.w;
    }
    if (t < 64) sb[t] = bias[t];
    constexpr int QR = K / 4;
    for (int i = t; i < 64 * QR; i += 256) {
        int r = i / QR, c = (i % QR) * 4;
        int gr = R0 + r;
        _Float16* p = &sA[r * SAP + c];
        if (gr < n) {
            if (c < Dm) {
                *(uint2*)p = *(const uint2*)&mean[(long)gr * Dm + c];
            } else {
                *(uint2*)p = *(const uint2*)&xd[(long)gr * Dd + (c - Dm)];
            }
        } else {
            p[0] = (_Float16)0.f; p[1] = (_Float16)0.f;
            p[2] = (_Float16)0.f; p[3] = (_Float16)0.f;
        }
    }
    __syncthreads();

    int w = t >> 6, lane = t & 63;
    int lr = lane & 15, lg = lane >> 4;
    f32x4 acc[4];
#pragma unroll
    for (int nt = 0; nt < 4; nt++) {
        float bb = sb[16 * nt + lr];
        acc[nt][0] = bb; acc[nt][1] = bb; acc[nt][2] = bb; acc[nt][3] = bb;
    }
    int arow = 16 * w + lr;
#pragma unroll
    for (int kk = 0; kk < K / 32; kk++) {
        int k0 = kk * 32 + 8 * lg;
        f16x8 a = *(const f16x8*)&sA[arow * SAP + k0];
#pragma unroll
        for (int nt = 0; nt < 4; nt++) {
            f16x8 b = *(const f16x8*)&sWt[(16 * nt + lr) * SAP + k0];
            acc[nt] = __builtin_amdgcn_mfma_f32_16x16x32_f16(a, b, acc[nt], 0, 0, 0);
        }
    }
#pragma unroll
    for (int nt = 0; nt < 4; nt++) {
#pragma unroll
        for (int r = 0; r < 4; r++) {
            int gr = R0 + 16 * w + lg * 4 + r;
            if (gr >= n) continue;
            float vv = acc[nt][r];
            if (RELU) vv = fmaxf(vv, 0.f);
            out[(long)gr * 64 + 16 * nt + lr] = __float2half(vv);
        }
    }
}

#define DENSE_SMEM_BYTES (64 * 136 * 2 * 2 + 256)

// layer-1 merged denses: [0,g1): um (K=96), rest: mu (K=128); xd from fp16 tables
__global__ __launch_bounds__(256) void dense_dual_l1(const __half* __restrict__ A_m,
                                                     const __half* __restrict__ xh_m,
                                                     const float* __restrict__ W1l_um,
                                                     const float* __restrict__ W1r_um,
                                                     const float* __restrict__ b1_um,
                                                     __half* __restrict__ Hh_m, int NM, int g1,
                                                     const __half* __restrict__ A_u,
                                                     const __half* __restrict__ xh_u,
                                                     const float* __restrict__ W1l_mu,
                                                     const float* __restrict__ W1r_mu,
                                                     const float* __restrict__ b1_mu,
                                                     __half* __restrict__ Hh_u, int NU) {
    __shared__ __align__(16) char smem[DENSE_SMEM_BYTES];
    if ((int)blockIdx.x < g1)
        dense_body<32, 64, true>(smem, A_m, xh_m, W1l_um, W1r_um, b1_um,
                                 Hh_m, NM, blockIdx.x);
    else
        dense_body<64, 32, true>(smem, A_u, xh_u, W1l_mu, W1r_mu, b1_mu,
                                 Hh_u, NU, blockIdx.x - g1);
}

// layer-2 merged denses: both K=128, fp16 in-place output over the mean buffers
__global__ __launch_bounds__(256) void dense_dual_l2(__half* __restrict__ A_m,
                                                     const __half* __restrict__ Hh_m,
                                                     const float* __restrict__ W2l_um,
                                                     const float* __restrict__ W2r_um,
                                                     const float* __restrict__ b2_um,
                                                     int NM, int g1,
                                                     __half* __restrict__ A_u,
                                                     const __half* __restrict__ Hh_u,
                                                     const float* __restrict__ W2l_mu,
                                                     const float* __restrict__ W2r_mu,
                                                     const float* __restrict__ b2_mu,
                                                     int NU) {
    __shared__ __align__(16) char smem[DENSE_SMEM_BYTES];
    if ((int)blockIdx.x < g1)
        dense_body<64, 64, false>(smem, A_m, Hh_m, W2l_um, W2r_um, b2_um,
                                  A_m, NM, blockIdx.x);
    else
        dense_body<64, 64, false>(smem, A_u, Hh_u, W2l_mu, W2r_mu, b2_mu,
                                  A_u, NU, blockIdx.x - g1);
}

// ---------------- merged head projections (z is fp16) ----------------

__global__ __launch_bounds__(256) void proj_dual(const __half* __restrict__ zu,
                                                 const __half* __restrict__ zm,
                                                 const float* __restrict__ Wlin,
                                                 const float* __restrict__ blin,
                                                 float2* __restrict__ pu,
                                                 float2* __restrict__ pm,
                                                 int NU, int NM, int gu) {
    int isu = ((int)blockIdx.x < gu);
    const __half* z = isu ? zu : zm;
    float2* p = isu ? pu : pm;
    int n = isu ? NU : NM;
    int woff = isu ? 0 : 64;
    int bid = isu ? blockIdx.x : blockIdx.x - gu;
    __shared__ float sW0[64], sW1[64];
    int t = threadIdx.x;
    if (t < 64) {
        sW0[t] = Wlin[(woff + t) * 2 + 0];
        sW1[t] = Wlin[(woff + t) * 2 + 1];
    }
    __syncthreads();
    float b0 = isu ? blin[0] : 0.f;
    float b1 = isu ? blin[1] : 0.f;
    int lane = t & 63;
    int w = t >> 6;
    int lr = lane & 15, q = lane >> 4;
    int row = bid * 16 + w * 4 + q;
    if (row >= n) return;
    uint2 raw = *(const uint2*)&z[(long)row * 64 + lr * 4];
    __half2 z01 = *(__half2*)&raw.x;
    __half2 z23 = *(__half2*)&raw.y;
    float2 f01 = __half22float2(z01);
    float2 f23 = __half22float2(z23);
    float p0 = f01.x * sW0[lr * 4] + f01.y * sW0[lr * 4 + 1] + f23.x * sW0[lr * 4 + 2] + f23.y * sW0[lr * 4 + 3];
    float p1 = f01.x * sW1[lr * 4] + f01.y * sW1[lr * 4 + 1] + f23.x * sW1[lr * 4 + 2] + f23.y * sW1[lr * 4 + 3];
#pragma unroll
    for (int m = 1; m < 16; m <<= 1) {
        p0 += __shfl_xor(p0, m, 64);
        p1 += __shfl_xor(p1, m, 64);
    }
    if (lr == 0) p[row] = make_float2(p0 + b0, p1 + b1);
}

// ---------------- head: two 8B gathers + softplus per label ----------------

__global__ __launch_bounds__(256) void head_gather(const float2* __restrict__ pu,
                                                   const float2* __restrict__ pm,
                                                   const int* __restrict__ lrow,
                                                   const int* __restrict__ lcol,
                                                   float* __restrict__ out, int B) {
    int i = blockIdx.x * blockDim.x + threadIdx.x;
    int st = gridDim.x * blockDim.x;
    for (int b = i; b < B; b += st) {
        float2 a = pu[lrow[b]];
        float2 d = pm[lcol[b]];
        float m = a.x + d.x;
        float x = a.y + d.y;
        float sp = fmaxf(x, 0.f) + log1pf(expf(-fabsf(x)));
        out[b] = m;
        out[B + b] = sp + 1e-6f;
    }
}

// ---------------- launch ----------------

extern "C" void kernel_launch(void* const* d_in, const int* in_sizes, int n_in,
                              void* d_out, int out_size, void* d_ws, size_t ws_size,
                              hipStream_t stream) {
    const float* x_user  = (const float*)d_in[0];
    const float* x_movie = (const float*)d_in[1];
    const int* src_um = (const int*)d_in[2];
    const int* dst_um = (const int*)d_in[3];
    const int* src_mu = (const int*)d_in[4];
    const int* dst_mu = (const int*)d_in[5];
    const int* lrow = (const int*)d_in[6];
    const int* lcol = (const int*)d_in[7];
    const float* W1_um_l = (const float*)d_in[8];
    const float* b1_um   = (const float*)d_in[9];
    const float* W1_um_r = (const float*)d_in[10];
    const float* W1_mu_l = (const float*)d_in[11];
    const float* b1_mu   = (const float*)d_in[12];
    const float* W1_mu_r = (const float*)d_in[13];
    const float* W2_um_l = (const float*)d_in[14];
    const float* b2_um   = (const float*)d_in[15];
    const float* W2_um_r = (const float*)d_in[16];
    const float* W2_mu_l = (const float*)d_in[17];
    const float* b2_mu   = (const float*)d_in[18];
    const float* W2_mu_r = (const float*)d_in[19];
    const float* W_lin   = (const float*)d_in[20];
    const float* b_lin   = (const float*)d_in[21];
    float* out = (float*)d_out;

    const int E  = in_sizes[2];
    const int B  = in_sizes[6];
    const int NU = in_sizes[0] / 32;   // 100000
    const int NM = in_sizes[1] / 64;   // 20000

    char* wsp = (char*)d_ws;
    size_t o = 0;
    auto alloc = [&](size_t bytes) {
        size_t p = o;
        o += (bytes + 255) & ~(size_t)255;
        return (void*)(wsp + p);
    };
    int* off_um = (int*)alloc((size_t)(NM + 1) * 4);
    int* off_mu = (int*)alloc((size_t)(NU + 1) * 4);
    int* boff   = (int*)alloc((NBALL + 1) * 4);
    int* csr_um = (int*)alloc((size_t)E * 4);
    int* csr_mu = (int*)alloc((size_t)E * 4);
    int* tmp    = (int*)alloc((size_t)2 * E * 4);        // packed bucketed edges
    __half* A_m  = (__half*)alloc((size_t)NM * 64 * 2);  // movie mean / z_movie (fp16)
    __half* A_u  = (__half*)alloc((size_t)NU * 64 * 2);  // user mean / z_user (fp16)
    __half* Hh_m = (__half*)alloc((size_t)NM * 64 * 2);  // h_movie fp16
    __half* Hh_u = (__half*)alloc((size_t)NU * 64 * 2);  // h_user fp16
    __half* xh_u = (__half*)alloc((size_t)NU * 32 * 2);  // x_user fp16
    __half* xh_m = (__half*)alloc((size_t)NM * 64 * 2);  // x_movie fp16
    float2* pu  = (float2*)alloc((size_t)NU * 8);        // user head projection
    float2* pm  = (float2*)alloc((size_t)NM * 8);        // movie head projection
    (void)ws_size;

    // histM aliases A_m: 177*256*4 = 181 KB; dead after partition2
    int* histM = (int*)A_m;

    const int chunk = (((E + NBLK - 1) / NBLK) + 3) & ~3;  // multiple of 4

    // 1) CSR build + fp16 casts
    hist_cast<<<NBLK + CAST_BLKS, 1024, 0, stream>>>(dst_um, dst_mu, histM, E, chunk,
                                                     x_user, xh_u, NU * 32,
                                                     x_movie, xh_m, NM * 64);
    totals_scan<<<1, 1024, 0, stream>>>(histM, boff, off_um, NM, off_mu, NU, E);
    partition2<<<NBLK, 1024, 0, stream>>>(src_um, dst_um, src_mu, dst_mu, histM, boff,
                                          tmp, E, chunk);
    scatter_both<<<NBALL, 1024, 0, stream>>>(tmp, boff, off_um, csr_um, NM,
                                             off_mu, csr_mu, NU, E);

    // 2) layer 1: merged aggs, then merged denses (xd from fp16 tables)
    {
        int g1 = (NM * 4 + 255) / 256;
        int g2 = (NU * 8 + 255) / 256;
        agg_dual_l1<<<g1 + g2, 256, 0, stream>>>(csr_um, off_um, xh_u, A_m, NM, g1,
                                                 csr_mu, off_mu, xh_m, A_u, NU);
        int d1 = (NM + 63) / 64, d2 = (NU + 63) / 64;
        dense_dual_l1<<<d1 + d2, 256, 0, stream>>>(A_m, xh_m, W1_um_l, W1_um_r, b1_um,
                                                   Hh_m, NM, d1,
                                                   A_u, xh_u, W1_mu_l, W1_mu_r, b1_mu,
                                                   Hh_u, NU);
    }

    // 3) layer 2: merged aggs, then merged denses (fp16 in-place over mean buffers)
    {
        int g1 = (NM * 8 + 255) / 256;
        int g2 = (NU * 8 + 255) / 256;
        agg_dual_l2<<<g1 + g2, 256, 0, stream>>>(csr_um, off_um, Hh_u, A_m, NM, g1,
                                                 csr_mu, off_mu, Hh_m, A_u, NU);
        int d1 = (NM + 63) / 64, d2 = (NU + 63) / 64;
        dense_dual_l2<<<d1 + d2, 256, 0, stream>>>(A_m, Hh_m, W2_um_l, W2_um_r, b2_um, NM, d1,
                                                   A_u, Hh_u, W2_mu_l, W2_mu_r, b2_mu, NU);
    }

    // 4) head: merged projections, then gather
    {
        int gu = (NU + 15) / 16, gm = (NM + 15) / 16;
        proj_dual<<<gu + gm, 256, 0, stream>>>(A_u, A_m, W_lin, b_lin, pu, pm, NU, NM, gu);
    }
    head_gather<<<1024, 256, 0, stream>>>(pu, pm, lrow, lcol, out, B);
}

// Round 17
// 231.615 us; speedup vs baseline: 1.0700x; 1.0319x over previous
//
#include <hip/hip_runtime.h>
#include <hip/hip_bf16.h>
#include <hip/hip_fp16.h>
#include <type_traits>

// combined bucket space: um buckets width 256 -> 79; mu buckets width 1024 -> 98
#define NB_UM 79
#define NB_MU 98
#define NBALL 177
#define NBLK 256
#define CAST_BLKS 64

using f16x8 = __attribute__((ext_vector_type(8))) _Float16;
using f32x4 = __attribute__((ext_vector_type(4))) float;

// ---------------- W^T prep: WT[c*(K+8)+k] = (k<Dm ? Wl[k*64+c] : Wr[(k-Dm)*64+c]) ----------------

__device__ __forceinline__ void wt_prep(const float* __restrict__ Wl,
                                        const float* __restrict__ Wr,
                                        int Dm, int K, __half* __restrict__ WT) {
    int SAP = K + 8;
    for (int i = threadIdx.x; i < 64 * K; i += 1024) {
        int c = i / K, k = i % K;
        float v = (k < Dm) ? Wl[k * 64 + c] : Wr[(k - Dm) * 64 + c];
        WT[c * SAP + k] = __float2half(v);
    }
}

// ---------------- pass 1: histogram + fp16 casts + W^T preps (merged) ----------------

__global__ __launch_bounds__(1024) void hist_cast(const int* __restrict__ dst_um,
                                                  const int* __restrict__ dst_mu,
                                                  int* __restrict__ histM, int E, int chunk,
                                                  const float* __restrict__ xu,
                                                  __half* __restrict__ xhu, int nu,
                                                  const float* __restrict__ xm,
                                                  __half* __restrict__ xhm, int nm,
                                                  const float* __restrict__ W1l_um,
                                                  const float* __restrict__ W1r_um,
                                                  const float* __restrict__ W1l_mu,
                                                  const float* __restrict__ W1r_mu,
                                                  const float* __restrict__ W2l_um,
                                                  const float* __restrict__ W2r_um,
                                                  const float* __restrict__ W2l_mu,
                                                  const float* __restrict__ W2r_mu,
                                                  __half* __restrict__ WT1_um,
                                                  __half* __restrict__ WT1_mu,
                                                  __half* __restrict__ WT2_um,
                                                  __half* __restrict__ WT2_mu) {
    int b = blockIdx.x;
    if (b >= NBLK + CAST_BLKS) {
        int w = b - NBLK - CAST_BLKS;
        if (w == 0) wt_prep(W1l_um, W1r_um, 32, 96, WT1_um);
        else if (w == 1) wt_prep(W1l_mu, W1r_mu, 64, 96, WT1_mu);
        else if (w == 2) wt_prep(W2l_um, W2r_um, 64, 128, WT2_um);
        else wt_prep(W2l_mu, W2r_mu, 64, 128, WT2_mu);
        return;
    }
    if (b >= NBLK) {
        int i = (b - NBLK) * 1024 + threadIdx.x;
        int st = CAST_BLKS * 1024;
        for (int k = i; k < nu / 2; k += st) {
            float2 v = ((const float2*)xu)[k];
            ((__half2*)xhu)[k] = __floats2half2_rn(v.x, v.y);
        }
        for (int k = i; k < nm / 2; k += st) {
            float2 v = ((const float2*)xm)[k];
            ((__half2*)xhm)[k] = __floats2half2_rn(v.x, v.y);
        }
        return;
    }
    __shared__ int h[NBALL];
    for (int i = threadIdx.x; i < NBALL; i += 1024) h[i] = 0;
    __syncthreads();
    int s = b * chunk, e = min(E, s + chunk);
    if (s < e) {
        int n4 = (e - s) >> 2;
        const int4* du4 = (const int4*)(dst_um + s);
        const int4* dm4 = (const int4*)(dst_mu + s);
        for (int i = threadIdx.x; i < n4; i += 1024) {
            int4 d = du4[i];
            atomicAdd(&h[d.x >> 8], 1);
            atomicAdd(&h[d.y >> 8], 1);
            atomicAdd(&h[d.z >> 8], 1);
            atomicAdd(&h[d.w >> 8], 1);
            int4 m = dm4[i];
            atomicAdd(&h[NB_UM + (m.x >> 10)], 1);
            atomicAdd(&h[NB_UM + (m.y >> 10)], 1);
            atomicAdd(&h[NB_UM + (m.z >> 10)], 1);
            atomicAdd(&h[NB_UM + (m.w >> 10)], 1);
        }
        for (int i = s + (n4 << 2) + threadIdx.x; i < e; i += 1024) {
            atomicAdd(&h[dst_um[i] >> 8], 1);
            atomicAdd(&h[NB_UM + (dst_mu[i] >> 10)], 1);
        }
    }
    __syncthreads();
    for (int i = threadIdx.x; i < NBALL; i += 1024) histM[i * NBLK + b] = h[i];
}

// ---------------- pass 2: per-bucket scan over blocks + bucket-total scan (merged) ----------------

__global__ __launch_bounds__(1024) void totals_scan(int* __restrict__ histM,
                                                    int* __restrict__ boff,
                                                    int* __restrict__ off_um, int NM,
                                                    int* __restrict__ off_mu, int NU, int E) {
    __shared__ int sbt[NBALL];
    __shared__ int sdata[256];
    int t = threadIdx.x;
    int wid = t >> 6, lane = t & 63;
    for (int w = wid; w < NBALL; w += 16) {
        int* row = histM + w * NBLK;
        int v[4];
        int s = 0;
#pragma unroll
        for (int i = 0; i < 4; i++) {
            int c = row[lane * 4 + i];
            v[i] = s;
            s += c;
        }
        int incl = s;
        for (int d = 1; d < 64; d <<= 1) {
            int y = __shfl_up(incl, d, 64);
            if (lane >= d) incl += y;
        }
        int excl = incl - s;
#pragma unroll
        for (int i = 0; i < 4; i++) row[lane * 4 + i] = excl + v[i];
        if (lane == 63) sbt[w] = incl;
    }
    __syncthreads();
    int v0 = 0;
    if (t < 256) {
        v0 = (t < NBALL) ? sbt[t] : 0;
        sdata[t] = v0;
    }
    __syncthreads();
    for (int d = 1; d < 256; d <<= 1) {
        int y = 0;
        if (t < 256 && t >= d) y = sdata[t - d];
        __syncthreads();
        if (t < 256) sdata[t] += y;
        __syncthreads();
    }
    if (t < NBALL) boff[t] = sdata[t] - v0;
    if (t == 0) {
        boff[NBALL] = 2 * E;
        off_um[NM] = E;
        off_mu[NU] = E;
    }
}

// ---------------- pass 3: partition (block-private cursors; cur = histM + boff) ----------------

__global__ __launch_bounds__(1024) void partition2(const int* __restrict__ src_um,
                                                   const int* __restrict__ dst_um,
                                                   const int* __restrict__ src_mu,
                                                   const int* __restrict__ dst_mu,
                                                   const int* __restrict__ histM,
                                                   const int* __restrict__ boff,
                                                   int* __restrict__ tmp, int E, int chunk) {
    __shared__ int cur[NBALL];
    int blk = blockIdx.x;
    for (int i = threadIdx.x; i < NBALL; i += 1024)
        cur[i] = histM[i * NBLK + blk] + boff[i];
    __syncthreads();
    int s = blk * chunk, e = min(E, s + chunk);
    if (s >= e) return;
    int n4 = (e - s) >> 2;
    const int4* su4 = (const int4*)(src_um + s);
    const int4* du4 = (const int4*)(dst_um + s);
    const int4* sm4 = (const int4*)(src_mu + s);
    const int4* dm4 = (const int4*)(dst_mu + s);
    for (int i = threadIdx.x; i < n4; i += 1024) {
        int4 sv = su4[i];
        int4 dv = du4[i];
        int p;
        p = atomicAdd(&cur[dv.x >> 8], 1); tmp[p] = sv.x | ((dv.x & 255) << 20);
        p = atomicAdd(&cur[dv.y >> 8], 1); tmp[p] = sv.y | ((dv.y & 255) << 20);
        p = atomicAdd(&cur[dv.z >> 8], 1); tmp[p] = sv.z | ((dv.z & 255) << 20);
        p = atomicAdd(&cur[dv.w >> 8], 1); tmp[p] = sv.w | ((dv.w & 255) << 20);
        int4 sv2 = sm4[i];
        int4 dv2 = dm4[i];
        p = atomicAdd(&cur[NB_UM + (dv2.x >> 10)], 1); tmp[p] = sv2.x | ((dv2.x & 1023) << 20);
        p = atomicAdd(&cur[NB_UM + (dv2.y >> 10)], 1); tmp[p] = sv2.y | ((dv2.y & 1023) << 20);
        p = atomicAdd(&cur[NB_UM + (dv2.z >> 10)], 1); tmp[p] = sv2.z | ((dv2.z & 1023) << 20);
        p = atomicAdd(&cur[NB_UM + (dv2.w >> 10)], 1); tmp[p] = sv2.w | ((dv2.w & 1023) << 20);
    }
    for (int i = s + (n4 << 2) + threadIdx.x; i < e; i += 1024) {
        int d = dst_um[i];
        int p = atomicAdd(&cur[d >> 8], 1);
        tmp[p] = src_um[i] | ((d & 255) << 20);
        int d2 = dst_mu[i];
        int q = atomicAdd(&cur[NB_UM + (d2 >> 10)], 1);
        tmp[q] = src_mu[i] | ((d2 & 1023) << 20);
    }
}

// ---------------- pass 4: per-bucket CSR scatter, both sides in one grid ----------------

__global__ __launch_bounds__(1024) void scatter_both(const int* __restrict__ tmp,
                                                     const int* __restrict__ boff,
                                                     int* __restrict__ off_um,
                                                     int* __restrict__ csr_um, int NM,
                                                     int* __restrict__ off_mu,
                                                     int* __restrict__ csr_mu, int NU, int E) {
    __shared__ int lcnt[1024];
    __shared__ int lcur[1024];
    __shared__ int sdata[1024];
    int b = blockIdx.x;
    int um = (b < NB_UM);
    int W = um ? 256 : 1024;
    int n = um ? NM : NU;
    int sub = um ? 0 : E;
    int* off = um ? off_um : off_mu;
    int* csr = um ? csr_um : csr_mu;
    int rowbase = (um ? b : (b - NB_UM)) * W;
    int t = threadIdx.x;
    int s = boff[b], e = boff[b + 1];
    for (int j = t; j < W; j += 1024) lcnt[j] = 0;
    __syncthreads();
    for (int i = s + t; i < e; i += 1024) atomicAdd(&lcnt[tmp[i] >> 20], 1);
    __syncthreads();
    int myc = (t < W) ? lcnt[t] : 0;
    sdata[t] = myc;
    __syncthreads();
    for (int d = 1; d < 1024; d <<= 1) {
        int y = (t >= d) ? sdata[t - d] : 0;
        __syncthreads();
        sdata[t] += y;
        __syncthreads();
    }
    if (t < W) lcur[t] = s + sdata[t] - myc;
    __syncthreads();
    for (int j = t; j < W; j += 1024)
        if (rowbase + j < n) off[rowbase + j] = lcur[j] - sub;
    __syncthreads();
    for (int i = s + t; i < e; i += 1024) {
        int vv = tmp[i];
        int p = atomicAdd(&lcur[vv >> 20], 1);
        csr[p - sub] = vv & 0xFFFFF;
    }
}

// ---------------- segment mean body (fp16 gather -> fp16 mean out, deep ILP) ----------------

__device__ __forceinline__ void acc8(float* a, uint4 r) {
    const __half2* h = reinterpret_cast<const __half2*>(&r);
#pragma unroll
    for (int j = 0; j < 4; j++) {
        float2 f = __half22float2(h[j]);
        a[2 * j] += f.x;
        a[2 * j + 1] += f.y;
    }
}

template <int D>
__device__ __forceinline__ void agg_body(const int* __restrict__ csr,
                                         const int* __restrict__ off,
                                         const __half* __restrict__ xh,
                                         __half* __restrict__ out, int nrows,
                                         int bid, int nblocks) {
    constexpr int L = D / 8;  // lanes per row
    int gid = (bid * 256 + (int)threadIdx.x) / L;
    int lg = threadIdx.x & (L - 1);
    int ngroups = (nblocks * 256) / L;
    int c8 = lg * 8;
    for (int row = gid; row < nrows; row += ngroups) {
        int s = off[row], e = off[row + 1];
        float a[8] = {0.f, 0.f, 0.f, 0.f, 0.f, 0.f, 0.f, 0.f};
        int k = s;
        for (; k + 8 <= e; k += 8) {
            uint4 r0 = *(const uint4*)&xh[(long)csr[k + 0] * D + c8];
            uint4 r1 = *(const uint4*)&xh[(long)csr[k + 1] * D + c8];
            uint4 r2 = *(const uint4*)&xh[(long)csr[k + 2] * D + c8];
            uint4 r3 = *(const uint4*)&xh[(long)csr[k + 3] * D + c8];
            uint4 r4 = *(const uint4*)&xh[(long)csr[k + 4] * D + c8];
            uint4 r5 = *(const uint4*)&xh[(long)csr[k + 5] * D + c8];
            uint4 r6 = *(const uint4*)&xh[(long)csr[k + 6] * D + c8];
            uint4 r7 = *(const uint4*)&xh[(long)csr[k + 7] * D + c8];
            acc8(a, r0); acc8(a, r1); acc8(a, r2); acc8(a, r3);
            acc8(a, r4); acc8(a, r5); acc8(a, r6); acc8(a, r7);
        }
        for (; k + 4 <= e; k += 4) {
            uint4 r0 = *(const uint4*)&xh[(long)csr[k + 0] * D + c8];
            uint4 r1 = *(const uint4*)&xh[(long)csr[k + 1] * D + c8];
            uint4 r2 = *(const uint4*)&xh[(long)csr[k + 2] * D + c8];
            uint4 r3 = *(const uint4*)&xh[(long)csr[k + 3] * D + c8];
            acc8(a, r0); acc8(a, r1); acc8(a, r2); acc8(a, r3);
        }
        for (; k < e; ++k) {
            uint4 r0 = *(const uint4*)&xh[(long)csr[k] * D + c8];
            acc8(a, r0);
        }
        float inv = 1.0f / fmaxf((float)(e - s), 1.0f);
        __half2 h0 = __floats2half2_rn(a[0] * inv, a[1] * inv);
        __half2 h1 = __floats2half2_rn(a[2] * inv, a[3] * inv);
        __half2 h2 = __floats2half2_rn(a[4] * inv, a[5] * inv);
        __half2 h3 = __floats2half2_rn(a[6] * inv, a[7] * inv);
        uint4 w;
        w.x = *(unsigned*)&h0; w.y = *(unsigned*)&h1;
        w.z = *(unsigned*)&h2; w.w = *(unsigned*)&h3;
        *(uint4*)&out[(long)row * D + c8] = w;
    }
}

// layer-1 merged aggs: blocks [0,g1): um D=32; [g1,..): mu D=64
__global__ __launch_bounds__(256) void agg_dual_l1(const int* __restrict__ csr_um,
                                                   const int* __restrict__ off_um,
                                                   const __half* __restrict__ xh_u,
                                                   __half* __restrict__ A_m, int NM, int g1,
                                                   const int* __restrict__ csr_mu,
                                                   const int* __restrict__ off_mu,
                                                   const __half* __restrict__ xh_m,
                                                   __half* __restrict__ A_u, int NU) {
    if ((int)blockIdx.x < g1)
        agg_body<32>(csr_um, off_um, xh_u, A_m, NM, blockIdx.x, g1);
    else
        agg_body<64>(csr_mu, off_mu, xh_m, A_u, NU, blockIdx.x - g1, gridDim.x - g1);
}

// layer-2 merged aggs: both D=64
__global__ __launch_bounds__(256) void agg_dual_l2(const int* __restrict__ csr_um,
                                                   const int* __restrict__ off_um,
                                                   const __half* __restrict__ Hh_u,
                                                   __half* __restrict__ A_m, int NM, int g1,
                                                   const int* __restrict__ csr_mu,
                                                   const int* __restrict__ off_mu,
                                                   const __half* __restrict__ Hh_m,
                                                   __half* __restrict__ A_u, int NU) {
    if ((int)blockIdx.x < g1)
        agg_body<64>(csr_um, off_um, Hh_u, A_m, NM, blockIdx.x, g1);
    else
        agg_body<64>(csr_mu, off_mu, Hh_m, A_u, NU, blockIdx.x - g1, gridDim.x - g1);
}

// ---------------- dense via MFMA body (mean fp16; xd fp16; W^T pre-transposed fp16) ----------------

template <int Dm, int Dd, bool RELU>
__device__ __forceinline__ void dense_body(char* smemraw,
                                           const __half* __restrict__ mean,
                                           const __half* __restrict__ xd,
                                           const __half* __restrict__ WT,
                                           const float* __restrict__ bias,
                                           __half* __restrict__ out, int n, int bid) {
    constexpr int K = Dm + Dd;     // 96 or 128
    constexpr int SAP = K + 8;
    _Float16* sA = (_Float16*)smemraw;
    _Float16* sWt = sA + 64 * SAP;
    float* sb = (float*)(sWt + 64 * SAP);
    int t = threadIdx.x;
    int R0 = bid * 64;

    // stage W^T: vectorized uint4 copies (LDS image identical to the old transpose)
    constexpr int WQ = 64 * SAP / 8;  // 8-half chunks; SAP divisible by 8
    for (int i = t; i < WQ; i += 256) {
        ((uint4*)sWt)[i] = ((const uint4*)WT)[i];
    }
    if (t < 64) sb[t] = bias[t];
    constexpr int QR = K / 4;
    for (int i = t; i < 64 * QR; i += 256) {
        int r = i / QR, c = (i % QR) * 4;
        int gr = R0 + r;
        _Float16* p = &sA[r * SAP + c];
        if (gr < n) {
            if (c < Dm) {
                *(uint2*)p = *(const uint2*)&mean[(long)gr * Dm + c];
            } else {
                *(uint2*)p = *(const uint2*)&xd[(long)gr * Dd + (c - Dm)];
            }
        } else {
            p[0] = (_Float16)0.f; p[1] = (_Float16)0.f;
            p[2] = (_Float16)0.f; p[3] = (_Float16)0.f;
        }
    }
    __syncthreads();

    int w = t >> 6, lane = t & 63;
    int lr = lane & 15, lg = lane >> 4;
    f32x4 acc[4];
#pragma unroll
    for (int nt = 0; nt < 4; nt++) {
        float bb = sb[16 * nt + lr];
        acc[nt][0] = bb; acc[nt][1] = bb; acc[nt][2] = bb; acc[nt][3] = bb;
    }
    int arow = 16 * w + lr;
#pragma unroll
    for (int kk = 0; kk < K / 32; kk++) {
        int k0 = kk * 32 + 8 * lg;
        f16x8 a = *(const f16x8*)&sA[arow * SAP + k0];
#pragma unroll
        for (int nt = 0; nt < 4; nt++) {
            f16x8 b = *(const f16x8*)&sWt[(16 * nt + lr) * SAP + k0];
            acc[nt] = __builtin_amdgcn_mfma_f32_16x16x32_f16(a, b, acc[nt], 0, 0, 0);
        }
    }
#pragma unroll
    for (int nt = 0; nt < 4; nt++) {
#pragma unroll
        for (int r = 0; r < 4; r++) {
            int gr = R0 + 16 * w + lg * 4 + r;
            if (gr >= n) continue;
            float vv = acc[nt][r];
            if (RELU) vv = fmaxf(vv, 0.f);
            out[(long)gr * 64 + 16 * nt + lr] = __float2half(vv);
        }
    }
}

#define DENSE_SMEM_BYTES (64 * 136 * 2 * 2 + 256)

// layer-1 merged denses: [0,g1): um (K=96), rest: mu (K=96); xd from fp16 tables
__global__ __launch_bounds__(256) void dense_dual_l1(const __half* __restrict__ A_m,
                                                     const __half* __restrict__ xh_m,
                                                     const __half* __restrict__ WT1_um,
                                                     const float* __restrict__ b1_um,
                                                     __half* __restrict__ Hh_m, int NM, int g1,
                                                     const __half* __restrict__ A_u,
                                                     const __half* __restrict__ xh_u,
                                                     const __half* __restrict__ WT1_mu,
                                                     const float* __restrict__ b1_mu,
                                                     __half* __restrict__ Hh_u, int NU) {
    __shared__ __align__(16) char smem[DENSE_SMEM_BYTES];
    if ((int)blockIdx.x < g1)
        dense_body<32, 64, true>(smem, A_m, xh_m, WT1_um, b1_um, Hh_m, NM, blockIdx.x);
    else
        dense_body<64, 32, true>(smem, A_u, xh_u, WT1_mu, b1_mu, Hh_u, NU, blockIdx.x - g1);
}

// layer-2 merged denses: both K=128, fp16 in-place output over the mean buffers
__global__ __launch_bounds__(256) void dense_dual_l2(__half* __restrict__ A_m,
                                                     const __half* __restrict__ Hh_m,
                                                     const __half* __restrict__ WT2_um,
                                                     const float* __restrict__ b2_um,
                                                     int NM, int g1,
                                                     __half* __restrict__ A_u,
                                                     const __half* __restrict__ Hh_u,
                                                     const __half* __restrict__ WT2_mu,
                                                     const float* __restrict__ b2_mu,
                                                     int NU) {
    __shared__ __align__(16) char smem[DENSE_SMEM_BYTES];
    if ((int)blockIdx.x < g1)
        dense_body<64, 64, false>(smem, A_m, Hh_m, WT2_um, b2_um, A_m, NM, blockIdx.x);
    else
        dense_body<64, 64, false>(smem, A_u, Hh_u, WT2_mu, b2_mu, A_u, NU, blockIdx.x - g1);
}

// ---------------- merged head projections (z is fp16) ----------------

__global__ __launch_bounds__(256) void proj_dual(const __half* __restrict__ zu,
                                                 const __half* __restrict__ zm,
                                                 const float* __restrict__ Wlin,
                                                 const float* __restrict__ blin,
                                                 float2* __restrict__ pu,
                                                 float2* __restrict__ pm,
                                                 int NU, int NM, int gu) {
    int isu = ((int)blockIdx.x < gu);
    const __half* z = isu ? zu : zm;
    float2* p = isu ? pu : pm;
    int n = isu ? NU : NM;
    int woff = isu ? 0 : 64;
    int bid = isu ? blockIdx.x : blockIdx.x - gu;
    __shared__ float sW0[64], sW1[64];
    int t = threadIdx.x;
    if (t < 64) {
        sW0[t] = Wlin[(woff + t) * 2 + 0];
        sW1[t] = Wlin[(woff + t) * 2 + 1];
    }
    __syncthreads();
    float b0 = isu ? blin[0] : 0.f;
    float b1 = isu ? blin[1] : 0.f;
    int lane = t & 63;
    int w = t >> 6;
    int lr = lane & 15, q = lane >> 4;
    int row = bid * 16 + w * 4 + q;
    if (row >= n) return;
    uint2 raw = *(const uint2*)&z[(long)row * 64 + lr * 4];
    __half2 z01 = *(__half2*)&raw.x;
    __half2 z23 = *(__half2*)&raw.y;
    float2 f01 = __half22float2(z01);
    float2 f23 = __half22float2(z23);
    float p0 = f01.x * sW0[lr * 4] + f01.y * sW0[lr * 4 + 1] + f23.x * sW0[lr * 4 + 2] + f23.y * sW0[lr * 4 + 3];
    float p1 = f01.x * sW1[lr * 4] + f01.y * sW1[lr * 4 + 1] + f23.x * sW1[lr * 4 + 2] + f23.y * sW1[lr * 4 + 3];
#pragma unroll
    for (int m = 1; m < 16; m <<= 1) {
        p0 += __shfl_xor(p0, m, 64);
        p1 += __shfl_xor(p1, m, 64);
    }
    if (lr == 0) p[row] = make_float2(p0 + b0, p1 + b1);
}

// ---------------- head: two 8B gathers + softplus per label ----------------

__global__ __launch_bounds__(256) void head_gather(const float2* __restrict__ pu,
                                                   const float2* __restrict__ pm,
                                                   const int* __restrict__ lrow,
                                                   const int* __restrict__ lcol,
                                                   float* __restrict__ out, int B) {
    int i = blockIdx.x * blockDim.x + threadIdx.x;
    int st = gridDim.x * blockDim.x;
    for (int b = i; b < B; b += st) {
        float2 a = pu[lrow[b]];
        float2 d = pm[lcol[b]];
        float m = a.x + d.x;
        float x = a.y + d.y;
        float sp = fmaxf(x, 0.f) + log1pf(expf(-fabsf(x)));
        out[b] = m;
        out[B + b] = sp + 1e-6f;
    }
}

// ---------------- launch ----------------

extern "C" void kernel_launch(void* const* d_in, const int* in_sizes, int n_in,
                              void* d_out, int out_size, void* d_ws, size_t ws_size,
                              hipStream_t stream) {
    const float* x_user  = (const float*)d_in[0];
    const float* x_movie = (const float*)d_in[1];
    const int* src_um = (const int*)d_in[2];
    const int* dst_um = (const int*)d_in[3];
    const int* src_mu = (const int*)d_in[4];
    const int* dst_mu = (const int*)d_in[5];
    const int* lrow = (const int*)d_in[6];
    const int* lcol = (const int*)d_in[7];
    const float* W1_um_l = (const float*)d_in[8];
    const float* b1_um   = (const float*)d_in[9];
    const float* W1_um_r = (const float*)d_in[10];
    const float* W1_mu_l = (const float*)d_in[11];
    const float* b1_mu   = (const float*)d_in[12];
    const float* W1_mu_r = (const float*)d_in[13];
    const float* W2_um_l = (const float*)d_in[14];
    const float* b2_um   = (const float*)d_in[15];
    const float* W2_um_r = (const float*)d_in[16];
    const float* W2_mu_l = (const float*)d_in[17];
    const float* b2_mu   = (const float*)d_in[18];
    const float* W2_mu_r = (const float*)d_in[19];
    const float* W_lin   = (const float*)d_in[20];
    const float* b_lin   = (const float*)d_in[21];
    float* out = (float*)d_out;

    const int E  = in_sizes[2];
    const int B  = in_sizes[6];
    const int NU = in_sizes[0] / 32;   // 100000
    const int NM = in_sizes[1] / 64;   // 20000

    char* wsp = (char*)d_ws;
    size_t o = 0;
    auto alloc = [&](size_t bytes) {
        size_t p = o;
        o += (bytes + 255) & ~(size_t)255;
        return (void*)(wsp + p);
    };
    int* off_um = (int*)alloc((size_t)(NM + 1) * 4);
    int* off_mu = (int*)alloc((size_t)(NU + 1) * 4);
    int* boff   = (int*)alloc((NBALL + 1) * 4);
    int* csr_um = (int*)alloc((size_t)E * 4);
    int* csr_mu = (int*)alloc((size_t)E * 4);
    int* tmp    = (int*)alloc((size_t)2 * E * 4);        // packed bucketed edges
    __half* A_m  = (__half*)alloc((size_t)NM * 64 * 2);  // movie mean / z_movie (fp16)
    __half* A_u  = (__half*)alloc((size_t)NU * 64 * 2);  // user mean / z_user (fp16)
    __half* Hh_m = (__half*)alloc((size_t)NM * 64 * 2);  // h_movie fp16
    __half* Hh_u = (__half*)alloc((size_t)NU * 64 * 2);  // h_user fp16
    __half* xh_u = (__half*)alloc((size_t)NU * 32 * 2);  // x_user fp16
    __half* xh_m = (__half*)alloc((size_t)NM * 64 * 2);  // x_movie fp16
    float2* pu  = (float2*)alloc((size_t)NU * 8);        // user head projection
    float2* pm  = (float2*)alloc((size_t)NM * 8);        // movie head projection
    __half* WT1_um = (__half*)alloc(64 * 104 * 2);       // W^T fp16, SAP=104 (K=96)
    __half* WT1_mu = (__half*)alloc(64 * 104 * 2);
    __half* WT2_um = (__half*)alloc(64 * 136 * 2);       // SAP=136 (K=128)
    __half* WT2_mu = (__half*)alloc(64 * 136 * 2);
    (void)ws_size;

    // histM aliases A_m: 177*256*4 = 181 KB; dead after partition2
    int* histM = (int*)A_m;

    const int chunk = (((E + NBLK - 1) / NBLK) + 3) & ~3;  // multiple of 4

    // 1) CSR build + fp16 casts + W^T preps
    hist_cast<<<NBLK + CAST_BLKS + 4, 1024, 0, stream>>>(
        dst_um, dst_mu, histM, E, chunk,
        x_user, xh_u, NU * 32, x_movie, xh_m, NM * 64,
        W1_um_l, W1_um_r, W1_mu_l, W1_mu_r, W2_um_l, W2_um_r, W2_mu_l, W2_mu_r,
        WT1_um, WT1_mu, WT2_um, WT2_mu);
    totals_scan<<<1, 1024, 0, stream>>>(histM, boff, off_um, NM, off_mu, NU, E);
    partition2<<<NBLK, 1024, 0, stream>>>(src_um, dst_um, src_mu, dst_mu, histM, boff,
                                          tmp, E, chunk);
    scatter_both<<<NBALL, 1024, 0, stream>>>(tmp, boff, off_um, csr_um, NM,
                                             off_mu, csr_mu, NU, E);

    // 2) layer 1: merged aggs, then merged denses
    {
        int g1 = (NM * 4 + 255) / 256;
        int g2 = (NU * 8 + 255) / 256;
        agg_dual_l1<<<g1 + g2, 256, 0, stream>>>(csr_um, off_um, xh_u, A_m, NM, g1,
                                                 csr_mu, off_mu, xh_m, A_u, NU);
        int d1 = (NM + 63) / 64, d2 = (NU + 63) / 64;
        dense_dual_l1<<<d1 + d2, 256, 0, stream>>>(A_m, xh_m, WT1_um, b1_um, Hh_m, NM, d1,
                                                   A_u, xh_u, WT1_mu, b1_mu, Hh_u, NU);
    }

    // 3) layer 2: merged aggs, then merged denses (fp16 in-place over mean buffers)
    {
        int g1 = (NM * 8 + 255) / 256;
        int g2 = (NU * 8 + 255) / 256;
        agg_dual_l2<<<g1 + g2, 256, 0, stream>>>(csr_um, off_um, Hh_u, A_m, NM, g1,
                                                 csr_mu, off_mu, Hh_m, A_u, NU);
        int d1 = (NM + 63) / 64, d2 = (NU + 63) / 64;
        dense_dual_l2<<<d1 + d2, 256, 0, stream>>>(A_m, Hh_m, WT2_um, b2_um, NM, d1,
                                                   A_u, Hh_u, WT2_mu, b2_mu, NU);
    }

    // 4) head: merged projections, then gather
    {
        int gu = (NU + 15) / 16, gm = (NM + 15) / 16;
        proj_dual<<<gu + gm, 256, 0, stream>>>(A_u, A_m, W_lin, b_lin, pu, pm, NU, NM, gu);
    }
    head_gather<<<1024, 256, 0, stream>>>(pu, pm, lrow, lcol, out, B);
}

// Round 18
// 224.314 us; speedup vs baseline: 1.1048x; 1.0325x over previous
//
#include <hip/hip_runtime.h>
#include <hip/hip_bf16.h>
#include <hip/hip_fp16.h>
#include <type_traits>

// combined bucket space: um buckets width 256 -> 79; mu buckets width 1024 -> 98
#define NB_UM 79
#define NB_MU 98
#define NBALL 177
#define NBLK 256
#define CAST_BLKS 64

using f16x8 = __attribute__((ext_vector_type(8))) _Float16;
using f32x4 = __attribute__((ext_vector_type(4))) float;

// ---------------- W^T prep ----------------

__device__ __forceinline__ void wt_prep(const float* __restrict__ Wl,
                                        const float* __restrict__ Wr,
                                        int Dm, int K, __half* __restrict__ WT) {
    int SAP = K + 8;
    for (int i = threadIdx.x; i < 64 * K; i += 1024) {
        int c = i / K, k = i % K;
        float v = (k < Dm) ? Wl[k * 64 + c] : Wr[(k - Dm) * 64 + c];
        WT[c * SAP + k] = __float2half(v);
    }
}

// ---------------- pass 1: histogram + fp16 casts + W^T preps (merged) ----------------

__global__ __launch_bounds__(1024) void hist_cast(const int* __restrict__ dst_um,
                                                  const int* __restrict__ dst_mu,
                                                  int* __restrict__ histM, int E, int chunk,
                                                  const float* __restrict__ xu,
                                                  __half* __restrict__ xhu, int nu,
                                                  const float* __restrict__ xm,
                                                  __half* __restrict__ xhm, int nm,
                                                  const float* __restrict__ W1l_um,
                                                  const float* __restrict__ W1r_um,
                                                  const float* __restrict__ W1l_mu,
                                                  const float* __restrict__ W1r_mu,
                                                  const float* __restrict__ W2l_um,
                                                  const float* __restrict__ W2r_um,
                                                  const float* __restrict__ W2l_mu,
                                                  const float* __restrict__ W2r_mu,
                                                  __half* __restrict__ WT1_um,
                                                  __half* __restrict__ WT1_mu,
                                                  __half* __restrict__ WT2_um,
                                                  __half* __restrict__ WT2_mu) {
    int b = blockIdx.x;
    if (b >= NBLK + CAST_BLKS) {
        int w = b - NBLK - CAST_BLKS;
        if (w == 0) wt_prep(W1l_um, W1r_um, 32, 96, WT1_um);
        else if (w == 1) wt_prep(W1l_mu, W1r_mu, 64, 96, WT1_mu);
        else if (w == 2) wt_prep(W2l_um, W2r_um, 64, 128, WT2_um);
        else wt_prep(W2l_mu, W2r_mu, 64, 128, WT2_mu);
        return;
    }
    if (b >= NBLK) {
        int i = (b - NBLK) * 1024 + threadIdx.x;
        int st = CAST_BLKS * 1024;
        for (int k = i; k < nu / 2; k += st) {
            float2 v = ((const float2*)xu)[k];
            ((__half2*)xhu)[k] = __floats2half2_rn(v.x, v.y);
        }
        for (int k = i; k < nm / 2; k += st) {
            float2 v = ((const float2*)xm)[k];
            ((__half2*)xhm)[k] = __floats2half2_rn(v.x, v.y);
        }
        return;
    }
    __shared__ int h[NBALL];
    for (int i = threadIdx.x; i < NBALL; i += 1024) h[i] = 0;
    __syncthreads();
    int s = b * chunk, e = min(E, s + chunk);
    if (s < e) {
        int n4 = (e - s) >> 2;
        const int4* du4 = (const int4*)(dst_um + s);
        const int4* dm4 = (const int4*)(dst_mu + s);
        for (int i = threadIdx.x; i < n4; i += 1024) {
            int4 d = du4[i];
            atomicAdd(&h[d.x >> 8], 1);
            atomicAdd(&h[d.y >> 8], 1);
            atomicAdd(&h[d.z >> 8], 1);
            atomicAdd(&h[d.w >> 8], 1);
            int4 m = dm4[i];
            atomicAdd(&h[NB_UM + (m.x >> 10)], 1);
            atomicAdd(&h[NB_UM + (m.y >> 10)], 1);
            atomicAdd(&h[NB_UM + (m.z >> 10)], 1);
            atomicAdd(&h[NB_UM + (m.w >> 10)], 1);
        }
        for (int i = s + (n4 << 2) + threadIdx.x; i < e; i += 1024) {
            atomicAdd(&h[dst_um[i] >> 8], 1);
            atomicAdd(&h[NB_UM + (dst_mu[i] >> 10)], 1);
        }
    }
    __syncthreads();
    for (int i = threadIdx.x; i < NBALL; i += 1024) histM[i * NBLK + b] = h[i];
}

// ---------------- pass 2: per-bucket scan over blocks + bucket-total scan ----------------

__global__ __launch_bounds__(1024) void totals_scan(int* __restrict__ histM,
                                                    int* __restrict__ boff,
                                                    int* __restrict__ off_um, int NM,
                                                    int* __restrict__ off_mu, int NU, int E) {
    __shared__ int sbt[NBALL];
    __shared__ int sdata[256];
    int t = threadIdx.x;
    int wid = t >> 6, lane = t & 63;
    for (int w = wid; w < NBALL; w += 16) {
        int* row = histM + w * NBLK;
        int v[4];
        int s = 0;
#pragma unroll
        for (int i = 0; i < 4; i++) {
            int c = row[lane * 4 + i];
            v[i] = s;
            s += c;
        }
        int incl = s;
        for (int d = 1; d < 64; d <<= 1) {
            int y = __shfl_up(incl, d, 64);
            if (lane >= d) incl += y;
        }
        int excl = incl - s;
#pragma unroll
        for (int i = 0; i < 4; i++) row[lane * 4 + i] = excl + v[i];
        if (lane == 63) sbt[w] = incl;
    }
    __syncthreads();
    int v0 = 0;
    if (t < 256) {
        v0 = (t < NBALL) ? sbt[t] : 0;
        sdata[t] = v0;
    }
    __syncthreads();
    for (int d = 1; d < 256; d <<= 1) {
        int y = 0;
        if (t < 256 && t >= d) y = sdata[t - d];
        __syncthreads();
        if (t < 256) sdata[t] += y;
        __syncthreads();
    }
    if (t < NBALL) boff[t] = sdata[t] - v0;
    if (t == 0) {
        boff[NBALL] = 2 * E;
        off_um[NM] = E;
        off_mu[NU] = E;
    }
}

// ---------------- pass 3: partition ----------------

__global__ __launch_bounds__(1024) void partition2(const int* __restrict__ src_um,
                                                   const int* __restrict__ dst_um,
                                                   const int* __restrict__ src_mu,
                                                   const int* __restrict__ dst_mu,
                                                   const int* __restrict__ histM,
                                                   const int* __restrict__ boff,
                                                   int* __restrict__ tmp, int E, int chunk) {
    __shared__ int cur[NBALL];
    int blk = blockIdx.x;
    for (int i = threadIdx.x; i < NBALL; i += 1024)
        cur[i] = histM[i * NBLK + blk] + boff[i];
    __syncthreads();
    int s = blk * chunk, e = min(E, s + chunk);
    if (s >= e) return;
    int n4 = (e - s) >> 2;
    const int4* su4 = (const int4*)(src_um + s);
    const int4* du4 = (const int4*)(dst_um + s);
    const int4* sm4 = (const int4*)(src_mu + s);
    const int4* dm4 = (const int4*)(dst_mu + s);
    for (int i = threadIdx.x; i < n4; i += 1024) {
        int4 sv = su4[i];
        int4 dv = du4[i];
        int p;
        p = atomicAdd(&cur[dv.x >> 8], 1); tmp[p] = sv.x | ((dv.x & 255) << 20);
        p = atomicAdd(&cur[dv.y >> 8], 1); tmp[p] = sv.y | ((dv.y & 255) << 20);
        p = atomicAdd(&cur[dv.z >> 8], 1); tmp[p] = sv.z | ((dv.z & 255) << 20);
        p = atomicAdd(&cur[dv.w >> 8], 1); tmp[p] = sv.w | ((dv.w & 255) << 20);
        int4 sv2 = sm4[i];
        int4 dv2 = dm4[i];
        p = atomicAdd(&cur[NB_UM + (dv2.x >> 10)], 1); tmp[p] = sv2.x | ((dv2.x & 1023) << 20);
        p = atomicAdd(&cur[NB_UM + (dv2.y >> 10)], 1); tmp[p] = sv2.y | ((dv2.y & 1023) << 20);
        p = atomicAdd(&cur[NB_UM + (dv2.z >> 10)], 1); tmp[p] = sv2.z | ((dv2.z & 1023) << 20);
        p = atomicAdd(&cur[NB_UM + (dv2.w >> 10)], 1); tmp[p] = sv2.w | ((dv2.w & 1023) << 20);
    }
    for (int i = s + (n4 << 2) + threadIdx.x; i < e; i += 1024) {
        int d = dst_um[i];
        int p = atomicAdd(&cur[d >> 8], 1);
        tmp[p] = src_um[i] | ((d & 255) << 20);
        int d2 = dst_mu[i];
        int q = atomicAdd(&cur[NB_UM + (d2 >> 10)], 1);
        tmp[q] = src_mu[i] | ((d2 & 1023) << 20);
    }
}

// ---------------- pass 4: per-bucket CSR scatter, both sides in one grid ----------------

__global__ __launch_bounds__(1024) void scatter_both(const int* __restrict__ tmp,
                                                     const int* __restrict__ boff,
                                                     int* __restrict__ off_um,
                                                     int* __restrict__ csr_um, int NM,
                                                     int* __restrict__ off_mu,
                                                     int* __restrict__ csr_mu, int NU, int E) {
    __shared__ int lcnt[1024];
    __shared__ int lcur[1024];
    __shared__ int sdata[1024];
    int b = blockIdx.x;
    int um = (b < NB_UM);
    int W = um ? 256 : 1024;
    int n = um ? NM : NU;
    int sub = um ? 0 : E;
    int* off = um ? off_um : off_mu;
    int* csr = um ? csr_um : csr_mu;
    int rowbase = (um ? b : (b - NB_UM)) * W;
    int t = threadIdx.x;
    int s = boff[b], e = boff[b + 1];
    for (int j = t; j < W; j += 1024) lcnt[j] = 0;
    __syncthreads();
    for (int i = s + t; i < e; i += 1024) atomicAdd(&lcnt[tmp[i] >> 20], 1);
    __syncthreads();
    int myc = (t < W) ? lcnt[t] : 0;
    sdata[t] = myc;
    __syncthreads();
    for (int d = 1; d < 1024; d <<= 1) {
        int y = (t >= d) ? sdata[t - d] : 0;
        __syncthreads();
        sdata[t] += y;
        __syncthreads();
    }
    if (t < W) lcur[t] = s + sdata[t] - myc;
    __syncthreads();
    for (int j = t; j < W; j += 1024)
        if (rowbase + j < n) off[rowbase + j] = lcur[j] - sub;
    __syncthreads();
    for (int i = s + t; i < e; i += 1024) {
        int vv = tmp[i];
        int p = atomicAdd(&lcur[vv >> 20], 1);
        csr[p - sub] = vv & 0xFFFFF;
    }
}

// ---------------- segment mean bodies (fp16 gather -> fp16 mean out) ----------------

__device__ __forceinline__ void acc8(float* a, uint4 r) {
    const __half2* h = reinterpret_cast<const __half2*>(&r);
#pragma unroll
    for (int j = 0; j < 4; j++) {
        float2 f = __half22float2(h[j]);
        a[2 * j] += f.x;
        a[2 * j + 1] += f.y;
    }
}

__device__ __forceinline__ void write_mean8(__half* __restrict__ out, long base,
                                            const float* a, float inv) {
    __half2 h0 = __floats2half2_rn(a[0] * inv, a[1] * inv);
    __half2 h1 = __floats2half2_rn(a[2] * inv, a[3] * inv);
    __half2 h2 = __floats2half2_rn(a[4] * inv, a[5] * inv);
    __half2 h3 = __floats2half2_rn(a[6] * inv, a[7] * inv);
    uint4 w;
    w.x = *(unsigned*)&h0; w.y = *(unsigned*)&h1;
    w.z = *(unsigned*)&h2; w.w = *(unsigned*)&h3;
    *(uint4*)&out[base] = w;
}

// group-per-row (low-degree rows: mu side, deg ~20)
template <int D>
__device__ __forceinline__ void agg_body(const int* __restrict__ csr,
                                         const int* __restrict__ off,
                                         const __half* __restrict__ xh,
                                         __half* __restrict__ out, int nrows,
                                         int bid, int nblocks) {
    constexpr int L = D / 8;
    int gid = (bid * 256 + (int)threadIdx.x) / L;
    int lg = threadIdx.x & (L - 1);
    int ngroups = (nblocks * 256) / L;
    int c8 = lg * 8;
    for (int row = gid; row < nrows; row += ngroups) {
        int s = off[row], e = off[row + 1];
        float a[8] = {0.f, 0.f, 0.f, 0.f, 0.f, 0.f, 0.f, 0.f};
        int k = s;
        for (; k + 8 <= e; k += 8) {
            uint4 r0 = *(const uint4*)&xh[(long)csr[k + 0] * D + c8];
            uint4 r1 = *(const uint4*)&xh[(long)csr[k + 1] * D + c8];
            uint4 r2 = *(const uint4*)&xh[(long)csr[k + 2] * D + c8];
            uint4 r3 = *(const uint4*)&xh[(long)csr[k + 3] * D + c8];
            uint4 r4 = *(const uint4*)&xh[(long)csr[k + 4] * D + c8];
            uint4 r5 = *(const uint4*)&xh[(long)csr[k + 5] * D + c8];
            uint4 r6 = *(const uint4*)&xh[(long)csr[k + 6] * D + c8];
            uint4 r7 = *(const uint4*)&xh[(long)csr[k + 7] * D + c8];
            acc8(a, r0); acc8(a, r1); acc8(a, r2); acc8(a, r3);
            acc8(a, r4); acc8(a, r5); acc8(a, r6); acc8(a, r7);
        }
        for (; k + 4 <= e; k += 4) {
            uint4 r0 = *(const uint4*)&xh[(long)csr[k + 0] * D + c8];
            uint4 r1 = *(const uint4*)&xh[(long)csr[k + 1] * D + c8];
            uint4 r2 = *(const uint4*)&xh[(long)csr[k + 2] * D + c8];
            uint4 r3 = *(const uint4*)&xh[(long)csr[k + 3] * D + c8];
            acc8(a, r0); acc8(a, r1); acc8(a, r2); acc8(a, r3);
        }
        for (; k < e; ++k) {
            uint4 r0 = *(const uint4*)&xh[(long)csr[k] * D + c8];
            acc8(a, r0);
        }
        float inv = 1.0f / fmaxf((float)(e - s), 1.0f);
        write_mean8(out, (long)row * D + c8, a, inv);
    }
}

// wave-per-row (high-degree rows: um side, deg ~100): 64/L edge slots in parallel,
// shfl_xor combine across slots (R6/R10-proven pattern).
template <int D>
__device__ __forceinline__ void agg_body_wave(const int* __restrict__ csr,
                                              const int* __restrict__ off,
                                              const __half* __restrict__ xh,
                                              __half* __restrict__ out, int nrows,
                                              int bid, int nblocks) {
    constexpr int L = D / 8;
    constexpr int SLOTS = 64 / L;
    int wid = (bid * 256 + (int)threadIdx.x) >> 6;
    int lane = threadIdx.x & 63;
    int nwaves = nblocks * 4;
    int g = lane / L;        // edge slot
    int c8 = (lane % L) * 8; // column group
    for (int row = wid; row < nrows; row += nwaves) {
        int s = off[row], e = off[row + 1];
        float a[8] = {0.f, 0.f, 0.f, 0.f, 0.f, 0.f, 0.f, 0.f};
        int k = s + g;
        for (; k + SLOTS < e; k += 2 * SLOTS) {
            uint4 r0 = *(const uint4*)&xh[(long)csr[k] * D + c8];
            uint4 r1 = *(const uint4*)&xh[(long)csr[k + SLOTS] * D + c8];
            acc8(a, r0);
            acc8(a, r1);
        }
        if (k < e) {
            uint4 r0 = *(const uint4*)&xh[(long)csr[k] * D + c8];
            acc8(a, r0);
        }
        for (int m = L; m < 64; m <<= 1) {
#pragma unroll
            for (int j = 0; j < 8; j++) a[j] += __shfl_xor(a[j], m, 64);
        }
        if (g == 0) {
            float inv = 1.0f / fmaxf((float)(e - s), 1.0f);
            write_mean8(out, (long)row * D + c8, a, inv);
        }
    }
}

// layer-1 merged aggs: blocks [0,g1): um D=32 wave-per-row; [g1,..): mu D=64 group-per-row
__global__ __launch_bounds__(256) void agg_dual_l1(const int* __restrict__ csr_um,
                                                   const int* __restrict__ off_um,
                                                   const __half* __restrict__ xh_u,
                                                   __half* __restrict__ A_m, int NM, int g1,
                                                   const int* __restrict__ csr_mu,
                                                   const int* __restrict__ off_mu,
                                                   const __half* __restrict__ xh_m,
                                                   __half* __restrict__ A_u, int NU) {
    if ((int)blockIdx.x < g1)
        agg_body_wave<32>(csr_um, off_um, xh_u, A_m, NM, blockIdx.x, g1);
    else
        agg_body<64>(csr_mu, off_mu, xh_m, A_u, NU, blockIdx.x - g1, gridDim.x - g1);
}

// layer-2 merged aggs: um D=64 wave-per-row; mu D=64 group-per-row
__global__ __launch_bounds__(256) void agg_dual_l2(const int* __restrict__ csr_um,
                                                   const int* __restrict__ off_um,
                                                   const __half* __restrict__ Hh_u,
                                                   __half* __restrict__ A_m, int NM, int g1,
                                                   const int* __restrict__ csr_mu,
                                                   const int* __restrict__ off_mu,
                                                   const __half* __restrict__ Hh_m,
                                                   __half* __restrict__ A_u, int NU) {
    if ((int)blockIdx.x < g1)
        agg_body_wave<64>(csr_um, off_um, Hh_u, A_m, NM, blockIdx.x, g1);
    else
        agg_body<64>(csr_mu, off_mu, Hh_m, A_u, NU, blockIdx.x - g1, gridDim.x - g1);
}

// ---------------- dense via MFMA body (mean fp16; xd fp16; W^T pre-transposed fp16) ----------------

template <int Dm, int Dd, bool RELU>
__device__ __forceinline__ void dense_body(char* smemraw,
                                           const __half* __restrict__ mean,
                                           const __half* __restrict__ xd,
                                           const __half* __restrict__ WT,
                                           const float* __restrict__ bias,
                                           __half* __restrict__ out, int n, int bid) {
    constexpr int K = Dm + Dd;
    constexpr int SAP = K + 8;
    _Float16* sA = (_Float16*)smemraw;
    _Float16* sWt = sA + 64 * SAP;
    float* sb = (float*)(sWt + 64 * SAP);
    int t = threadIdx.x;
    int R0 = bid * 64;

    constexpr int WQ = 64 * SAP / 8;
    for (int i = t; i < WQ; i += 256) {
        ((uint4*)sWt)[i] = ((const uint4*)WT)[i];
    }
    if (t < 64) sb[t] = bias[t];
    constexpr int QR = K / 4;
    for (int i = t; i < 64 * QR; i += 256) {
        int r = i / QR, c = (i % QR) * 4;
        int gr = R0 + r;
        _Float16* p = &sA[r * SAP + c];
        if (gr < n) {
            if (c < Dm) {
                *(uint2*)p = *(const uint2*)&mean[(long)gr * Dm + c];
            } else {
                *(uint2*)p = *(const uint2*)&xd[(long)gr * Dd + (c - Dm)];
            }
        } else {
            p[0] = (_Float16)0.f; p[1] = (_Float16)0.f;
            p[2] = (_Float16)0.f; p[3] = (_Float16)0.f;
        }
    }
    __syncthreads();

    int w = t >> 6, lane = t & 63;
    int lr = lane & 15, lg = lane >> 4;
    f32x4 acc[4];
#pragma unroll
    for (int nt = 0; nt < 4; nt++) {
        float bb = sb[16 * nt + lr];
        acc[nt][0] = bb; acc[nt][1] = bb; acc[nt][2] = bb; acc[nt][3] = bb;
    }
    int arow = 16 * w + lr;
#pragma unroll
    for (int kk = 0; kk < K / 32; kk++) {
        int k0 = kk * 32 + 8 * lg;
        f16x8 a = *(const f16x8*)&sA[arow * SAP + k0];
#pragma unroll
        for (int nt = 0; nt < 4; nt++) {
            f16x8 b = *(const f16x8*)&sWt[(16 * nt + lr) * SAP + k0];
            acc[nt] = __builtin_amdgcn_mfma_f32_16x16x32_f16(a, b, acc[nt], 0, 0, 0);
        }
    }
#pragma unroll
    for (int nt = 0; nt < 4; nt++) {
#pragma unroll
        for (int r = 0; r < 4; r++) {
            int gr = R0 + 16 * w + lg * 4 + r;
            if (gr >= n) continue;
            float vv = acc[nt][r];
            if (RELU) vv = fmaxf(vv, 0.f);
            out[(long)gr * 64 + 16 * nt + lr] = __float2half(vv);
        }
    }
}

#define DENSE_SMEM_BYTES (64 * 136 * 2 * 2 + 256)

__global__ __launch_bounds__(256) void dense_dual_l1(const __half* __restrict__ A_m,
                                                     const __half* __restrict__ xh_m,
                                                     const __half* __restrict__ WT1_um,
                                                     const float* __restrict__ b1_um,
                                                     __half* __restrict__ Hh_m, int NM, int g1,
                                                     const __half* __restrict__ A_u,
                                                     const __half* __restrict__ xh_u,
                                                     const __half* __restrict__ WT1_mu,
                                                     const float* __restrict__ b1_mu,
                                                     __half* __restrict__ Hh_u, int NU) {
    __shared__ __align__(16) char smem[DENSE_SMEM_BYTES];
    if ((int)blockIdx.x < g1)
        dense_body<32, 64, true>(smem, A_m, xh_m, WT1_um, b1_um, Hh_m, NM, blockIdx.x);
    else
        dense_body<64, 32, true>(smem, A_u, xh_u, WT1_mu, b1_mu, Hh_u, NU, blockIdx.x - g1);
}

__global__ __launch_bounds__(256) void dense_dual_l2(__half* __restrict__ A_m,
                                                     const __half* __restrict__ Hh_m,
                                                     const __half* __restrict__ WT2_um,
                                                     const float* __restrict__ b2_um,
                                                     int NM, int g1,
                                                     __half* __restrict__ A_u,
                                                     const __half* __restrict__ Hh_u,
                                                     const __half* __restrict__ WT2_mu,
                                                     const float* __restrict__ b2_mu,
                                                     int NU) {
    __shared__ __align__(16) char smem[DENSE_SMEM_BYTES];
    if ((int)blockIdx.x < g1)
        dense_body<64, 64, false>(smem, A_m, Hh_m, WT2_um, b2_um, A_m, NM, blockIdx.x);
    else
        dense_body<64, 64, false>(smem, A_u, Hh_u, WT2_mu, b2_mu, A_u, NU, blockIdx.x - g1);
}

// ---------------- merged head projections (z is fp16) ----------------

__global__ __launch_bounds__(256) void proj_dual(const __half* __restrict__ zu,
                                                 const __half* __restrict__ zm,
                                                 const float* __restrict__ Wlin,
                                                 const float* __restrict__ blin,
                                                 float2* __restrict__ pu,
                                                 float2* __restrict__ pm,
                                                 int NU, int NM, int gu) {
    int isu = ((int)blockIdx.x < gu);
    const __half* z = isu ? zu : zm;
    float2* p = isu ? pu : pm;
    int n = isu ? NU : NM;
    int woff = isu ? 0 : 64;
    int bid = isu ? blockIdx.x : blockIdx.x - gu;
    __shared__ float sW0[64], sW1[64];
    int t = threadIdx.x;
    if (t < 64) {
        sW0[t] = Wlin[(woff + t) * 2 + 0];
        sW1[t] = Wlin[(woff + t) * 2 + 1];
    }
    __syncthreads();
    float b0 = isu ? blin[0] : 0.f;
    float b1 = isu ? blin[1] : 0.f;
    int lane = t & 63;
    int w = t >> 6;
    int lr = lane & 15, q = lane >> 4;
    int row = bid * 16 + w * 4 + q;
    if (row >= n) return;
    uint2 raw = *(const uint2*)&z[(long)row * 64 + lr * 4];
    __half2 z01 = *(__half2*)&raw.x;
    __half2 z23 = *(__half2*)&raw.y;
    float2 f01 = __half22float2(z01);
    float2 f23 = __half22float2(z23);
    float p0 = f01.x * sW0[lr * 4] + f01.y * sW0[lr * 4 + 1] + f23.x * sW0[lr * 4 + 2] + f23.y * sW0[lr * 4 + 3];
    float p1 = f01.x * sW1[lr * 4] + f01.y * sW1[lr * 4 + 1] + f23.x * sW1[lr * 4 + 2] + f23.y * sW1[lr * 4 + 3];
#pragma unroll
    for (int m = 1; m < 16; m <<= 1) {
        p0 += __shfl_xor(p0, m, 64);
        p1 += __shfl_xor(p1, m, 64);
    }
    if (lr == 0) p[row] = make_float2(p0 + b0, p1 + b1);
}

// ---------------- head: two 8B gathers + softplus per label ----------------

__global__ __launch_bounds__(256) void head_gather(const float2* __restrict__ pu,
                                                   const float2* __restrict__ pm,
                                                   const int* __restrict__ lrow,
                                                   const int* __restrict__ lcol,
                                                   float* __restrict__ out, int B) {
    int i = blockIdx.x * blockDim.x + threadIdx.x;
    int st = gridDim.x * blockDim.x;
    for (int b = i; b < B; b += st) {
        float2 a = pu[lrow[b]];
        float2 d = pm[lcol[b]];
        float m = a.x + d.x;
        float x = a.y + d.y;
        float sp = fmaxf(x, 0.f) + log1pf(expf(-fabsf(x)));
        out[b] = m;
        out[B + b] = sp + 1e-6f;
    }
}

// ---------------- launch ----------------

extern "C" void kernel_launch(void* const* d_in, const int* in_sizes, int n_in,
                              void* d_out, int out_size, void* d_ws, size_t ws_size,
                              hipStream_t stream) {
    const float* x_user  = (const float*)d_in[0];
    const float* x_movie = (const float*)d_in[1];
    const int* src_um = (const int*)d_in[2];
    const int* dst_um = (const int*)d_in[3];
    const int* src_mu = (const int*)d_in[4];
    const int* dst_mu = (const int*)d_in[5];
    const int* lrow = (const int*)d_in[6];
    const int* lcol = (const int*)d_in[7];
    const float* W1_um_l = (const float*)d_in[8];
    const float* b1_um   = (const float*)d_in[9];
    const float* W1_um_r = (const float*)d_in[10];
    const float* W1_mu_l = (const float*)d_in[11];
    const float* b1_mu   = (const float*)d_in[12];
    const float* W1_mu_r = (const float*)d_in[13];
    const float* W2_um_l = (const float*)d_in[14];
    const float* b2_um   = (const float*)d_in[15];
    const float* W2_um_r = (const float*)d_in[16];
    const float* W2_mu_l = (const float*)d_in[17];
    const float* b2_mu   = (const float*)d_in[18];
    const float* W2_mu_r = (const float*)d_in[19];
    const float* W_lin   = (const float*)d_in[20];
    const float* b_lin   = (const float*)d_in[21];
    float* out = (float*)d_out;

    const int E  = in_sizes[2];
    const int B  = in_sizes[6];
    const int NU = in_sizes[0] / 32;   // 100000
    const int NM = in_sizes[1] / 64;   // 20000

    char* wsp = (char*)d_ws;
    size_t o = 0;
    auto alloc = [&](size_t bytes) {
        size_t p = o;
        o += (bytes + 255) & ~(size_t)255;
        return (void*)(wsp + p);
    };
    int* off_um = (int*)alloc((size_t)(NM + 1) * 4);
    int* off_mu = (int*)alloc((size_t)(NU + 1) * 4);
    int* boff   = (int*)alloc((NBALL + 1) * 4);
    int* csr_um = (int*)alloc((size_t)E * 4);
    int* csr_mu = (int*)alloc((size_t)E * 4);
    int* tmp    = (int*)alloc((size_t)2 * E * 4);
    __half* A_m  = (__half*)alloc((size_t)NM * 64 * 2);
    __half* A_u  = (__half*)alloc((size_t)NU * 64 * 2);
    __half* Hh_m = (__half*)alloc((size_t)NM * 64 * 2);
    __half* Hh_u = (__half*)alloc((size_t)NU * 64 * 2);
    __half* xh_u = (__half*)alloc((size_t)NU * 32 * 2);
    __half* xh_m = (__half*)alloc((size_t)NM * 64 * 2);
    float2* pu  = (float2*)alloc((size_t)NU * 8);
    float2* pm  = (float2*)alloc((size_t)NM * 8);
    __half* WT1_um = (__half*)alloc(64 * 104 * 2);
    __half* WT1_mu = (__half*)alloc(64 * 104 * 2);
    __half* WT2_um = (__half*)alloc(64 * 136 * 2);
    __half* WT2_mu = (__half*)alloc(64 * 136 * 2);
    (void)ws_size;

    int* histM = (int*)A_m;  // 181 KB; dead after partition2

    const int chunk = (((E + NBLK - 1) / NBLK) + 3) & ~3;

    // 1) CSR build + fp16 casts + W^T preps
    hist_cast<<<NBLK + CAST_BLKS + 4, 1024, 0, stream>>>(
        dst_um, dst_mu, histM, E, chunk,
        x_user, xh_u, NU * 32, x_movie, xh_m, NM * 64,
        W1_um_l, W1_um_r, W1_mu_l, W1_mu_r, W2_um_l, W2_um_r, W2_mu_l, W2_mu_r,
        WT1_um, WT1_mu, WT2_um, WT2_mu);
    totals_scan<<<1, 1024, 0, stream>>>(histM, boff, off_um, NM, off_mu, NU, E);
    partition2<<<NBLK, 1024, 0, stream>>>(src_um, dst_um, src_mu, dst_mu, histM, boff,
                                          tmp, E, chunk);
    scatter_both<<<NBALL, 1024, 0, stream>>>(tmp, boff, off_um, csr_um, NM,
                                             off_mu, csr_mu, NU, E);

    // 2) layer 1: merged aggs (um wave-per-row), then merged denses
    {
        int g1 = (NM + 3) / 4;           // um: one wave per row
        int g2 = (NU * 8 + 255) / 256;   // mu: 8-lane group per row
        agg_dual_l1<<<g1 + g2, 256, 0, stream>>>(csr_um, off_um, xh_u, A_m, NM, g1,
                                                 csr_mu, off_mu, xh_m, A_u, NU);
        int d1 = (NM + 63) / 64, d2 = (NU + 63) / 64;
        dense_dual_l1<<<d1 + d2, 256, 0, stream>>>(A_m, xh_m, WT1_um, b1_um, Hh_m, NM, d1,
                                                   A_u, xh_u, WT1_mu, b1_mu, Hh_u, NU);
    }

    // 3) layer 2: merged aggs (um wave-per-row), then merged denses
    {
        int g1 = (NM + 3) / 4;
        int g2 = (NU * 8 + 255) / 256;
        agg_dual_l2<<<g1 + g2, 256, 0, stream>>>(csr_um, off_um, Hh_u, A_m, NM, g1,
                                                 csr_mu, off_mu, Hh_m, A_u, NU);
        int d1 = (NM + 63) / 64, d2 = (NU + 63) / 64;
        dense_dual_l2<<<d1 + d2, 256, 0, stream>>>(A_m, Hh_m, WT2_um, b2_um, NM, d1,
                                                   A_u, Hh_u, WT2_mu, b2_mu, NU);
    }

    // 4) head: merged projections, then gather
    {
        int gu = (NU + 15) / 16, gm = (NM + 15) / 16;
        proj_dual<<<gu + gm, 256, 0, stream>>>(A_u, A_m, W_lin, b_lin, pu, pm, NU, NM, gu);
    }
    head_gather<<<1024, 256, 0, stream>>>(pu, pm, lrow, lcol, out, B);
}

// Round 19
// 221.542 us; speedup vs baseline: 1.1186x; 1.0125x over previous
//
#include <hip/hip_runtime.h>
#include <hip/hip_bf16.h>
#include <hip/hip_fp16.h>
#include <type_traits>

// combined bucket space: um buckets width 256 -> 79; mu buckets width 1024 -> 98
#define NB_UM 79
#define NB_MU 98
#define NBALL 177
#define NBLK 256
#define CAST_BLKS 64

using f16x8 = __attribute__((ext_vector_type(8))) _Float16;
using f32x4 = __attribute__((ext_vector_type(4))) float;

// ---------------- W^T prep ----------------

__device__ __forceinline__ void wt_prep(const float* __restrict__ Wl,
                                        const float* __restrict__ Wr,
                                        int Dm, int K, __half* __restrict__ WT) {
    int SAP = K + 8;
    for (int i = threadIdx.x; i < 64 * K; i += 1024) {
        int c = i / K, k = i % K;
        float v = (k < Dm) ? Wl[k * 64 + c] : Wr[(k - Dm) * 64 + c];
        WT[c * SAP + k] = __float2half(v);
    }
}

// ---------------- pass 1: histogram + fp16 casts + W^T preps (merged) ----------------

__global__ __launch_bounds__(1024) void hist_cast(const int* __restrict__ dst_um,
                                                  const int* __restrict__ dst_mu,
                                                  int* __restrict__ histM, int E, int chunk,
                                                  const float* __restrict__ xu,
                                                  __half* __restrict__ xhu, int nu,
                                                  const float* __restrict__ xm,
                                                  __half* __restrict__ xhm, int nm,
                                                  const float* __restrict__ W1l_um,
                                                  const float* __restrict__ W1r_um,
                                                  const float* __restrict__ W1l_mu,
                                                  const float* __restrict__ W1r_mu,
                                                  const float* __restrict__ W2l_um,
                                                  const float* __restrict__ W2r_um,
                                                  const float* __restrict__ W2l_mu,
                                                  const float* __restrict__ W2r_mu,
                                                  __half* __restrict__ WT1_um,
                                                  __half* __restrict__ WT1_mu,
                                                  __half* __restrict__ WT2_um,
                                                  __half* __restrict__ WT2_mu) {
    int b = blockIdx.x;
    if (b >= NBLK + CAST_BLKS) {
        int w = b - NBLK - CAST_BLKS;
        if (w == 0) wt_prep(W1l_um, W1r_um, 32, 96, WT1_um);
        else if (w == 1) wt_prep(W1l_mu, W1r_mu, 64, 96, WT1_mu);
        else if (w == 2) wt_prep(W2l_um, W2r_um, 64, 128, WT2_um);
        else wt_prep(W2l_mu, W2r_mu, 64, 128, WT2_mu);
        return;
    }
    if (b >= NBLK) {
        int i = (b - NBLK) * 1024 + threadIdx.x;
        int st = CAST_BLKS * 1024;
        for (int k = i; k < nu / 2; k += st) {
            float2 v = ((const float2*)xu)[k];
            ((__half2*)xhu)[k] = __floats2half2_rn(v.x, v.y);
        }
        for (int k = i; k < nm / 2; k += st) {
            float2 v = ((const float2*)xm)[k];
            ((__half2*)xhm)[k] = __floats2half2_rn(v.x, v.y);
        }
        return;
    }
    __shared__ int h[NBALL];
    for (int i = threadIdx.x; i < NBALL; i += 1024) h[i] = 0;
    __syncthreads();
    int s = b * chunk, e = min(E, s + chunk);
    if (s < e) {
        int n4 = (e - s) >> 2;
        const int4* du4 = (const int4*)(dst_um + s);
        const int4* dm4 = (const int4*)(dst_mu + s);
        for (int i = threadIdx.x; i < n4; i += 1024) {
            int4 d = du4[i];
            atomicAdd(&h[d.x >> 8], 1);
            atomicAdd(&h[d.y >> 8], 1);
            atomicAdd(&h[d.z >> 8], 1);
            atomicAdd(&h[d.w >> 8], 1);
            int4 m = dm4[i];
            atomicAdd(&h[NB_UM + (m.x >> 10)], 1);
            atomicAdd(&h[NB_UM + (m.y >> 10)], 1);
            atomicAdd(&h[NB_UM + (m.z >> 10)], 1);
            atomicAdd(&h[NB_UM + (m.w >> 10)], 1);
        }
        for (int i = s + (n4 << 2) + threadIdx.x; i < e; i += 1024) {
            atomicAdd(&h[dst_um[i] >> 8], 1);
            atomicAdd(&h[NB_UM + (dst_mu[i] >> 10)], 1);
        }
    }
    __syncthreads();
    for (int i = threadIdx.x; i < NBALL; i += 1024) histM[i * NBLK + b] = h[i];
}

// ---------------- pass 2: per-bucket scan over blocks + bucket-total scan ----------------

__global__ __launch_bounds__(1024) void totals_scan(int* __restrict__ histM,
                                                    int* __restrict__ boff,
                                                    int* __restrict__ off_um, int NM,
                                                    int* __restrict__ off_mu, int NU, int E) {
    __shared__ int sbt[NBALL];
    __shared__ int sdata[256];
    int t = threadIdx.x;
    int wid = t >> 6, lane = t & 63;
    for (int w = wid; w < NBALL; w += 16) {
        int* row = histM + w * NBLK;
        int v[4];
        int s = 0;
#pragma unroll
        for (int i = 0; i < 4; i++) {
            int c = row[lane * 4 + i];
            v[i] = s;
            s += c;
        }
        int incl = s;
        for (int d = 1; d < 64; d <<= 1) {
            int y = __shfl_up(incl, d, 64);
            if (lane >= d) incl += y;
        }
        int excl = incl - s;
#pragma unroll
        for (int i = 0; i < 4; i++) row[lane * 4 + i] = excl + v[i];
        if (lane == 63) sbt[w] = incl;
    }
    __syncthreads();
    int v0 = 0;
    if (t < 256) {
        v0 = (t < NBALL) ? sbt[t] : 0;
        sdata[t] = v0;
    }
    __syncthreads();
    for (int d = 1; d < 256; d <<= 1) {
        int y = 0;
        if (t < 256 && t >= d) y = sdata[t - d];
        __syncthreads();
        if (t < 256) sdata[t] += y;
        __syncthreads();
    }
    if (t < NBALL) boff[t] = sdata[t] - v0;
    if (t == 0) {
        boff[NBALL] = 2 * E;
        off_um[NM] = E;
        off_mu[NU] = E;
    }
}

// ---------------- pass 3: partition ----------------

__global__ __launch_bounds__(1024) void partition2(const int* __restrict__ src_um,
                                                   const int* __restrict__ dst_um,
                                                   const int* __restrict__ src_mu,
                                                   const int* __restrict__ dst_mu,
                                                   const int* __restrict__ histM,
                                                   const int* __restrict__ boff,
                                                   int* __restrict__ tmp, int E, int chunk) {
    __shared__ int cur[NBALL];
    int blk = blockIdx.x;
    for (int i = threadIdx.x; i < NBALL; i += 1024)
        cur[i] = histM[i * NBLK + blk] + boff[i];
    __syncthreads();
    int s = blk * chunk, e = min(E, s + chunk);
    if (s >= e) return;
    int n4 = (e - s) >> 2;
    const int4* su4 = (const int4*)(src_um + s);
    const int4* du4 = (const int4*)(dst_um + s);
    const int4* sm4 = (const int4*)(src_mu + s);
    const int4* dm4 = (const int4*)(dst_mu + s);
    for (int i = threadIdx.x; i < n4; i += 1024) {
        int4 sv = su4[i];
        int4 dv = du4[i];
        int p;
        p = atomicAdd(&cur[dv.x >> 8], 1); tmp[p] = sv.x | ((dv.x & 255) << 20);
        p = atomicAdd(&cur[dv.y >> 8], 1); tmp[p] = sv.y | ((dv.y & 255) << 20);
        p = atomicAdd(&cur[dv.z >> 8], 1); tmp[p] = sv.z | ((dv.z & 255) << 20);
        p = atomicAdd(&cur[dv.w >> 8], 1); tmp[p] = sv.w | ((dv.w & 255) << 20);
        int4 sv2 = sm4[i];
        int4 dv2 = dm4[i];
        p = atomicAdd(&cur[NB_UM + (dv2.x >> 10)], 1); tmp[p] = sv2.x | ((dv2.x & 1023) << 20);
        p = atomicAdd(&cur[NB_UM + (dv2.y >> 10)], 1); tmp[p] = sv2.y | ((dv2.y & 1023) << 20);
        p = atomicAdd(&cur[NB_UM + (dv2.z >> 10)], 1); tmp[p] = sv2.z | ((dv2.z & 1023) << 20);
        p = atomicAdd(&cur[NB_UM + (dv2.w >> 10)], 1); tmp[p] = sv2.w | ((dv2.w & 1023) << 20);
    }
    for (int i = s + (n4 << 2) + threadIdx.x; i < e; i += 1024) {
        int d = dst_um[i];
        int p = atomicAdd(&cur[d >> 8], 1);
        tmp[p] = src_um[i] | ((d & 255) << 20);
        int d2 = dst_mu[i];
        int q = atomicAdd(&cur[NB_UM + (d2 >> 10)], 1);
        tmp[q] = src_mu[i] | ((d2 & 1023) << 20);
    }
}

// ---------------- pass 4: per-bucket CSR scatter, both sides in one grid ----------------

__global__ __launch_bounds__(1024) void scatter_both(const int* __restrict__ tmp,
                                                     const int* __restrict__ boff,
                                                     int* __restrict__ off_um,
                                                     int* __restrict__ csr_um, int NM,
                                                     int* __restrict__ off_mu,
                                                     int* __restrict__ csr_mu, int NU, int E) {
    __shared__ int lcnt[1024];
    __shared__ int lcur[1024];
    __shared__ int sdata[1024];
    int b = blockIdx.x;
    int um = (b < NB_UM);
    int W = um ? 256 : 1024;
    int n = um ? NM : NU;
    int sub = um ? 0 : E;
    int* off = um ? off_um : off_mu;
    int* csr = um ? csr_um : csr_mu;
    int rowbase = (um ? b : (b - NB_UM)) * W;
    int t = threadIdx.x;
    int s = boff[b], e = boff[b + 1];
    for (int j = t; j < W; j += 1024) lcnt[j] = 0;
    __syncthreads();
    for (int i = s + t; i < e; i += 1024) atomicAdd(&lcnt[tmp[i] >> 20], 1);
    __syncthreads();
    int myc = (t < W) ? lcnt[t] : 0;
    sdata[t] = myc;
    __syncthreads();
    for (int d = 1; d < 1024; d <<= 1) {
        int y = (t >= d) ? sdata[t - d] : 0;
        __syncthreads();
        sdata[t] += y;
        __syncthreads();
    }
    if (t < W) lcur[t] = s + sdata[t] - myc;
    __syncthreads();
    for (int j = t; j < W; j += 1024)
        if (rowbase + j < n) off[rowbase + j] = lcur[j] - sub;
    __syncthreads();
    for (int i = s + t; i < e; i += 1024) {
        int vv = tmp[i];
        int p = atomicAdd(&lcur[vv >> 20], 1);
        csr[p - sub] = vv & 0xFFFFF;
    }
}

// ---------------- segment mean bodies (fp16 gather -> fp16 mean out) ----------------

__device__ __forceinline__ void acc8(float* a, uint4 r) {
    const __half2* h = reinterpret_cast<const __half2*>(&r);
#pragma unroll
    for (int j = 0; j < 4; j++) {
        float2 f = __half22float2(h[j]);
        a[2 * j] += f.x;
        a[2 * j + 1] += f.y;
    }
}

__device__ __forceinline__ void write_mean8(__half* __restrict__ out, long base,
                                            const float* a, float inv) {
    __half2 h0 = __floats2half2_rn(a[0] * inv, a[1] * inv);
    __half2 h1 = __floats2half2_rn(a[2] * inv, a[3] * inv);
    __half2 h2 = __floats2half2_rn(a[4] * inv, a[5] * inv);
    __half2 h3 = __floats2half2_rn(a[6] * inv, a[7] * inv);
    uint4 w;
    w.x = *(unsigned*)&h0; w.y = *(unsigned*)&h1;
    w.z = *(unsigned*)&h2; w.w = *(unsigned*)&h3;
    *(uint4*)&out[base] = w;
}

// group-per-row (low-degree rows: mu side, deg ~20)
template <int D>
__device__ __forceinline__ void agg_body(const int* __restrict__ csr,
                                         const int* __restrict__ off,
                                         const __half* __restrict__ xh,
                                         __half* __restrict__ out, int nrows,
                                         int bid, int nblocks) {
    constexpr int L = D / 8;
    int gid = (bid * 256 + (int)threadIdx.x) / L;
    int lg = threadIdx.x & (L - 1);
    int ngroups = (nblocks * 256) / L;
    int c8 = lg * 8;
    for (int row = gid; row < nrows; row += ngroups) {
        int s = off[row], e = off[row + 1];
        float a[8] = {0.f, 0.f, 0.f, 0.f, 0.f, 0.f, 0.f, 0.f};
        int k = s;
        for (; k + 8 <= e; k += 8) {
            uint4 r0 = *(const uint4*)&xh[(long)csr[k + 0] * D + c8];
            uint4 r1 = *(const uint4*)&xh[(long)csr[k + 1] * D + c8];
            uint4 r2 = *(const uint4*)&xh[(long)csr[k + 2] * D + c8];
            uint4 r3 = *(const uint4*)&xh[(long)csr[k + 3] * D + c8];
            uint4 r4 = *(const uint4*)&xh[(long)csr[k + 4] * D + c8];
            uint4 r5 = *(const uint4*)&xh[(long)csr[k + 5] * D + c8];
            uint4 r6 = *(const uint4*)&xh[(long)csr[k + 6] * D + c8];
            uint4 r7 = *(const uint4*)&xh[(long)csr[k + 7] * D + c8];
            acc8(a, r0); acc8(a, r1); acc8(a, r2); acc8(a, r3);
            acc8(a, r4); acc8(a, r5); acc8(a, r6); acc8(a, r7);
        }
        for (; k + 4 <= e; k += 4) {
            uint4 r0 = *(const uint4*)&xh[(long)csr[k + 0] * D + c8];
            uint4 r1 = *(const uint4*)&xh[(long)csr[k + 1] * D + c8];
            uint4 r2 = *(const uint4*)&xh[(long)csr[k + 2] * D + c8];
            uint4 r3 = *(const uint4*)&xh[(long)csr[k + 3] * D + c8];
            acc8(a, r0); acc8(a, r1); acc8(a, r2); acc8(a, r3);
        }
        for (; k < e; ++k) {
            uint4 r0 = *(const uint4*)&xh[(long)csr[k] * D + c8];
            acc8(a, r0);
        }
        float inv = 1.0f / fmaxf((float)(e - s), 1.0f);
        write_mean8(out, (long)row * D + c8, a, inv);
    }
}

// wave-per-row (high-degree rows: um side, deg ~100), 4-deep ILP
template <int D>
__device__ __forceinline__ void agg_body_wave(const int* __restrict__ csr,
                                              const int* __restrict__ off,
                                              const __half* __restrict__ xh,
                                              __half* __restrict__ out, int nrows,
                                              int bid, int nblocks) {
    constexpr int L = D / 8;
    constexpr int SLOTS = 64 / L;
    int wid = (bid * 256 + (int)threadIdx.x) >> 6;
    int lane = threadIdx.x & 63;
    int nwaves = nblocks * 4;
    int g = lane / L;        // edge slot
    int c8 = (lane % L) * 8; // column group
    for (int row = wid; row < nrows; row += nwaves) {
        int s = off[row], e = off[row + 1];
        float a[8] = {0.f, 0.f, 0.f, 0.f, 0.f, 0.f, 0.f, 0.f};
        int k = s + g;
        // 4 independent gathers in flight per slot-lane
        for (; k + 3 * SLOTS < e; k += 4 * SLOTS) {
            uint4 r0 = *(const uint4*)&xh[(long)csr[k] * D + c8];
            uint4 r1 = *(const uint4*)&xh[(long)csr[k + SLOTS] * D + c8];
            uint4 r2 = *(const uint4*)&xh[(long)csr[k + 2 * SLOTS] * D + c8];
            uint4 r3 = *(const uint4*)&xh[(long)csr[k + 3 * SLOTS] * D + c8];
            acc8(a, r0); acc8(a, r1); acc8(a, r2); acc8(a, r3);
        }
        for (; k + SLOTS < e; k += 2 * SLOTS) {
            uint4 r0 = *(const uint4*)&xh[(long)csr[k] * D + c8];
            uint4 r1 = *(const uint4*)&xh[(long)csr[k + SLOTS] * D + c8];
            acc8(a, r0);
            acc8(a, r1);
        }
        if (k < e) {
            uint4 r0 = *(const uint4*)&xh[(long)csr[k] * D + c8];
            acc8(a, r0);
        }
        for (int m = L; m < 64; m <<= 1) {
#pragma unroll
            for (int j = 0; j < 8; j++) a[j] += __shfl_xor(a[j], m, 64);
        }
        if (g == 0) {
            float inv = 1.0f / fmaxf((float)(e - s), 1.0f);
            write_mean8(out, (long)row * D + c8, a, inv);
        }
    }
}

// layer-1 merged aggs: blocks [0,g1): um D=32 wave-per-row; [g1,..): mu D=64 group-per-row
__global__ __launch_bounds__(256) void agg_dual_l1(const int* __restrict__ csr_um,
                                                   const int* __restrict__ off_um,
                                                   const __half* __restrict__ xh_u,
                                                   __half* __restrict__ A_m, int NM, int g1,
                                                   const int* __restrict__ csr_mu,
                                                   const int* __restrict__ off_mu,
                                                   const __half* __restrict__ xh_m,
                                                   __half* __restrict__ A_u, int NU) {
    if ((int)blockIdx.x < g1)
        agg_body_wave<32>(csr_um, off_um, xh_u, A_m, NM, blockIdx.x, g1);
    else
        agg_body<64>(csr_mu, off_mu, xh_m, A_u, NU, blockIdx.x - g1, gridDim.x - g1);
}

// layer-2 merged aggs: um D=64 wave-per-row; mu D=64 group-per-row
__global__ __launch_bounds__(256) void agg_dual_l2(const int* __restrict__ csr_um,
                                                   const int* __restrict__ off_um,
                                                   const __half* __restrict__ Hh_u,
                                                   __half* __restrict__ A_m, int NM, int g1,
                                                   const int* __restrict__ csr_mu,
                                                   const int* __restrict__ off_mu,
                                                   const __half* __restrict__ Hh_m,
                                                   __half* __restrict__ A_u, int NU) {
    if ((int)blockIdx.x < g1)
        agg_body_wave<64>(csr_um, off_um, Hh_u, A_m, NM, blockIdx.x, g1);
    else
        agg_body<64>(csr_mu, off_mu, Hh_m, A_u, NU, blockIdx.x - g1, gridDim.x - g1);
}

// ---------------- dense via MFMA body (mean fp16; xd fp16; W^T pre-transposed fp16) ----------------

template <int Dm, int Dd, bool RELU>
__device__ __forceinline__ void dense_body(char* smemraw,
                                           const __half* __restrict__ mean,
                                           const __half* __restrict__ xd,
                                           const __half* __restrict__ WT,
                                           const float* __restrict__ bias,
                                           __half* __restrict__ out, int n, int bid) {
    constexpr int K = Dm + Dd;
    constexpr int SAP = K + 8;
    _Float16* sA = (_Float16*)smemraw;
    _Float16* sWt = sA + 64 * SAP;
    float* sb = (float*)(sWt + 64 * SAP);
    int t = threadIdx.x;
    int R0 = bid * 64;

    constexpr int WQ = 64 * SAP / 8;
    for (int i = t; i < WQ; i += 256) {
        ((uint4*)sWt)[i] = ((const uint4*)WT)[i];
    }
    if (t < 64) sb[t] = bias[t];
    constexpr int QR = K / 4;
    for (int i = t; i < 64 * QR; i += 256) {
        int r = i / QR, c = (i % QR) * 4;
        int gr = R0 + r;
        _Float16* p = &sA[r * SAP + c];
        if (gr < n) {
            if (c < Dm) {
                *(uint2*)p = *(const uint2*)&mean[(long)gr * Dm + c];
            } else {
                *(uint2*)p = *(const uint2*)&xd[(long)gr * Dd + (c - Dm)];
            }
        } else {
            p[0] = (_Float16)0.f; p[1] = (_Float16)0.f;
            p[2] = (_Float16)0.f; p[3] = (_Float16)0.f;
        }
    }
    __syncthreads();

    int w = t >> 6, lane = t & 63;
    int lr = lane & 15, lg = lane >> 4;
    f32x4 acc[4];
#pragma unroll
    for (int nt = 0; nt < 4; nt++) {
        float bb = sb[16 * nt + lr];
        acc[nt][0] = bb; acc[nt][1] = bb; acc[nt][2] = bb; acc[nt][3] = bb;
    }
    int arow = 16 * w + lr;
#pragma unroll
    for (int kk = 0; kk < K / 32; kk++) {
        int k0 = kk * 32 + 8 * lg;
        f16x8 a = *(const f16x8*)&sA[arow * SAP + k0];
#pragma unroll
        for (int nt = 0; nt < 4; nt++) {
            f16x8 b = *(const f16x8*)&sWt[(16 * nt + lr) * SAP + k0];
            acc[nt] = __builtin_amdgcn_mfma_f32_16x16x32_f16(a, b, acc[nt], 0, 0, 0);
        }
    }
#pragma unroll
    for (int nt = 0; nt < 4; nt++) {
#pragma unroll
        for (int r = 0; r < 4; r++) {
            int gr = R0 + 16 * w + lg * 4 + r;
            if (gr >= n) continue;
            float vv = acc[nt][r];
            if (RELU) vv = fmaxf(vv, 0.f);
            out[(long)gr * 64 + 16 * nt + lr] = __float2half(vv);
        }
    }
}

#define DENSE_SMEM_BYTES (64 * 136 * 2 * 2 + 256)

__global__ __launch_bounds__(256) void dense_dual_l1(const __half* __restrict__ A_m,
                                                     const __half* __restrict__ xh_m,
                                                     const __half* __restrict__ WT1_um,
                                                     const float* __restrict__ b1_um,
                                                     __half* __restrict__ Hh_m, int NM, int g1,
                                                     const __half* __restrict__ A_u,
                                                     const __half* __restrict__ xh_u,
                                                     const __half* __restrict__ WT1_mu,
                                                     const float* __restrict__ b1_mu,
                                                     __half* __restrict__ Hh_u, int NU) {
    __shared__ __align__(16) char smem[DENSE_SMEM_BYTES];
    if ((int)blockIdx.x < g1)
        dense_body<32, 64, true>(smem, A_m, xh_m, WT1_um, b1_um, Hh_m, NM, blockIdx.x);
    else
        dense_body<64, 32, true>(smem, A_u, xh_u, WT1_mu, b1_mu, Hh_u, NU, blockIdx.x - g1);
}

__global__ __launch_bounds__(256) void dense_dual_l2(__half* __restrict__ A_m,
                                                     const __half* __restrict__ Hh_m,
                                                     const __half* __restrict__ WT2_um,
                                                     const float* __restrict__ b2_um,
                                                     int NM, int g1,
                                                     __half* __restrict__ A_u,
                                                     const __half* __restrict__ Hh_u,
                                                     const __half* __restrict__ WT2_mu,
                                                     const float* __restrict__ b2_mu,
                                                     int NU) {
    __shared__ __align__(16) char smem[DENSE_SMEM_BYTES];
    if ((int)blockIdx.x < g1)
        dense_body<64, 64, false>(smem, A_m, Hh_m, WT2_um, b2_um, A_m, NM, blockIdx.x);
    else
        dense_body<64, 64, false>(smem, A_u, Hh_u, WT2_mu, b2_mu, A_u, NU, blockIdx.x - g1);
}

// ---------------- merged head projections (z is fp16) ----------------

__global__ __launch_bounds__(256) void proj_dual(const __half* __restrict__ zu,
                                                 const __half* __restrict__ zm,
                                                 const float* __restrict__ Wlin,
                                                 const float* __restrict__ blin,
                                                 float2* __restrict__ pu,
                                                 float2* __restrict__ pm,
                                                 int NU, int NM, int gu) {
    int isu = ((int)blockIdx.x < gu);
    const __half* z = isu ? zu : zm;
    float2* p = isu ? pu : pm;
    int n = isu ? NU : NM;
    int woff = isu ? 0 : 64;
    int bid = isu ? blockIdx.x : blockIdx.x - gu;
    __shared__ float sW0[64], sW1[64];
    int t = threadIdx.x;
    if (t < 64) {
        sW0[t] = Wlin[(woff + t) * 2 + 0];
        sW1[t] = Wlin[(woff + t) * 2 + 1];
    }
    __syncthreads();
    float b0 = isu ? blin[0] : 0.f;
    float b1 = isu ? blin[1] : 0.f;
    int lane = t & 63;
    int w = t >> 6;
    int lr = lane & 15, q = lane >> 4;
    int row = bid * 16 + w * 4 + q;
    if (row >= n) return;
    uint2 raw = *(const uint2*)&z[(long)row * 64 + lr * 4];
    __half2 z01 = *(__half2*)&raw.x;
    __half2 z23 = *(__half2*)&raw.y;
    float2 f01 = __half22float2(z01);
    float2 f23 = __half22float2(z23);
    float p0 = f01.x * sW0[lr * 4] + f01.y * sW0[lr * 4 + 1] + f23.x * sW0[lr * 4 + 2] + f23.y * sW0[lr * 4 + 3];
    float p1 = f01.x * sW1[lr * 4] + f01.y * sW1[lr * 4 + 1] + f23.x * sW1[lr * 4 + 2] + f23.y * sW1[lr * 4 + 3];
#pragma unroll
    for (int m = 1; m < 16; m <<= 1) {
        p0 += __shfl_xor(p0, m, 64);
        p1 += __shfl_xor(p1, m, 64);
    }
    if (lr == 0) p[row] = make_float2(p0 + b0, p1 + b1);
}

// ---------------- head: two 8B gathers + softplus per label ----------------

__global__ __launch_bounds__(256) void head_gather(const float2* __restrict__ pu,
                                                   const float2* __restrict__ pm,
                                                   const int* __restrict__ lrow,
                                                   const int* __restrict__ lcol,
                                                   float* __restrict__ out, int B) {
    int i = blockIdx.x * blockDim.x + threadIdx.x;
    int st = gridDim.x * blockDim.x;
    for (int b = i; b < B; b += st) {
        float2 a = pu[lrow[b]];
        float2 d = pm[lcol[b]];
        float m = a.x + d.x;
        float x = a.y + d.y;
        float sp = fmaxf(x, 0.f) + log1pf(expf(-fabsf(x)));
        out[b] = m;
        out[B + b] = sp + 1e-6f;
    }
}

// ---------------- launch ----------------

extern "C" void kernel_launch(void* const* d_in, const int* in_sizes, int n_in,
                              void* d_out, int out_size, void* d_ws, size_t ws_size,
                              hipStream_t stream) {
    const float* x_user  = (const float*)d_in[0];
    const float* x_movie = (const float*)d_in[1];
    const int* src_um = (const int*)d_in[2];
    const int* dst_um = (const int*)d_in[3];
    const int* src_mu = (const int*)d_in[4];
    const int* dst_mu = (const int*)d_in[5];
    const int* lrow = (const int*)d_in[6];
    const int* lcol = (const int*)d_in[7];
    const float* W1_um_l = (const float*)d_in[8];
    const float* b1_um   = (const float*)d_in[9];
    const float* W1_um_r = (const float*)d_in[10];
    const float* W1_mu_l = (const float*)d_in[11];
    const float* b1_mu   = (const float*)d_in[12];
    const float* W1_mu_r = (const float*)d_in[13];
    const float* W2_um_l = (const float*)d_in[14];
    const float* b2_um   = (const float*)d_in[15];
    const float* W2_um_r = (const float*)d_in[16];
    const float* W2_mu_l = (const float*)d_in[17];
    const float* b2_mu   = (const float*)d_in[18];
    const float* W2_mu_r = (const float*)d_in[19];
    const float* W_lin   = (const float*)d_in[20];
    const float* b_lin   = (const float*)d_in[21];
    float* out = (float*)d_out;

    const int E  = in_sizes[2];
    const int B  = in_sizes[6];
    const int NU = in_sizes[0] / 32;   // 100000
    const int NM = in_sizes[1] / 64;   // 20000

    char* wsp = (char*)d_ws;
    size_t o = 0;
    auto alloc = [&](size_t bytes) {
        size_t p = o;
        o += (bytes + 255) & ~(size_t)255;
        return (void*)(wsp + p);
    };
    int* off_um = (int*)alloc((size_t)(NM + 1) * 4);
    int* off_mu = (int*)alloc((size_t)(NU + 1) * 4);
    int* boff   = (int*)alloc((NBALL + 1) * 4);
    int* csr_um = (int*)alloc((size_t)E * 4);
    int* csr_mu = (int*)alloc((size_t)E * 4);
    int* tmp    = (int*)alloc((size_t)2 * E * 4);
    __half* A_m  = (__half*)alloc((size_t)NM * 64 * 2);
    __half* A_u  = (__half*)alloc((size_t)NU * 64 * 2);
    __half* Hh_m = (__half*)alloc((size_t)NM * 64 * 2);
    __half* Hh_u = (__half*)alloc((size_t)NU * 64 * 2);
    __half* xh_u = (__half*)alloc((size_t)NU * 32 * 2);
    __half* xh_m = (__half*)alloc((size_t)NM * 64 * 2);
    float2* pu  = (float2*)alloc((size_t)NU * 8);
    float2* pm  = (float2*)alloc((size_t)NM * 8);
    __half* WT1_um = (__half*)alloc(64 * 104 * 2);
    __half* WT1_mu = (__half*)alloc(64 * 104 * 2);
    __half* WT2_um = (__half*)alloc(64 * 136 * 2);
    __half* WT2_mu = (__half*)alloc(64 * 136 * 2);
    (void)ws_size;

    int* histM = (int*)A_m;  // 181 KB; dead after partition2

    const int chunk = (((E + NBLK - 1) / NBLK) + 3) & ~3;

    // 1) CSR build + fp16 casts + W^T preps
    hist_cast<<<NBLK + CAST_BLKS + 4, 1024, 0, stream>>>(
        dst_um, dst_mu, histM, E, chunk,
        x_user, xh_u, NU * 32, x_movie, xh_m, NM * 64,
        W1_um_l, W1_um_r, W1_mu_l, W1_mu_r, W2_um_l, W2_um_r, W2_mu_l, W2_mu_r,
        WT1_um, WT1_mu, WT2_um, WT2_mu);
    totals_scan<<<1, 1024, 0, stream>>>(histM, boff, off_um, NM, off_mu, NU, E);
    partition2<<<NBLK, 1024, 0, stream>>>(src_um, dst_um, src_mu, dst_mu, histM, boff,
                                          tmp, E, chunk);
    scatter_both<<<NBALL, 1024, 0, stream>>>(tmp, boff, off_um, csr_um, NM,
                                             off_mu, csr_mu, NU, E);

    // 2) layer 1: merged aggs (um wave-per-row), then merged denses
    {
        int g1 = (NM + 3) / 4;           // um: one wave per row
        int g2 = (NU * 8 + 255) / 256;   // mu: 8-lane group per row
        agg_dual_l1<<<g1 + g2, 256, 0, stream>>>(csr_um, off_um, xh_u, A_m, NM, g1,
                                                 csr_mu, off_mu, xh_m, A_u, NU);
        int d1 = (NM + 63) / 64, d2 = (NU + 63) / 64;
        dense_dual_l1<<<d1 + d2, 256, 0, stream>>>(A_m, xh_m, WT1_um, b1_um, Hh_m, NM, d1,
                                                   A_u, xh_u, WT1_mu, b1_mu, Hh_u, NU);
    }

    // 3) layer 2: merged aggs (um wave-per-row), then merged denses
    {
        int g1 = (NM + 3) / 4;
        int g2 = (NU * 8 + 255) / 256;
        agg_dual_l2<<<g1 + g2, 256, 0, stream>>>(csr_um, off_um, Hh_u, A_m, NM, g1,
                                                 csr_mu, off_mu, Hh_m, A_u, NU);
        int d1 = (NM + 63) / 64, d2 = (NU + 63) / 64;
        dense_dual_l2<<<d1 + d2, 256, 0, stream>>>(A_m, Hh_m, WT2_um, b2_um, NM, d1,
                                                   A_u, Hh_u, WT2_mu, b2_mu, NU);
    }

    // 4) head: merged projections, then gather
    {
        int gu = (NU + 15) / 16, gm = (NM + 15) / 16;
        proj_dual<<<gu + gm, 256, 0, stream>>>(A_u, A_m, W_lin, b_lin, pu, pm, NU, NM, gu);
    }
    head_gather<<<1024, 256, 0, stream>>>(pu, pm, lrow, lcol, out, B);
}